// Round 1
// baseline (193289.832 us; speedup 1.0000x reference)
//
#include <hip/hip_runtime.h>
#include <hip/hip_fp16.h>
#include <math.h>

// ---------------------------------------------------------------------------
// Decoder (ESPnet AttDot + 2x LSTMCell + CE) on gfx950.
// B=32 T=512 EPROJS=512 DUNITS=1024 ATT_DIM=320 ODIM=10000 L=128 (129 steps)
// Strategy:
//   * f16 weights/activations (fp32 accumulate, fp32 state) -- halves traffic,
//     enables v_dot2_f32_f16. Loss precision budget has ~30x margin.
//   * persistent kernel for the 129-step scan; 640 blocks x 256 thr,
//     __launch_bounds__(256,3) guarantees co-residency (640 <= 3*256-ish);
//     monotonic device-scope barrier (no reset => no ABA).
//   * logits GEMM: f16 MFMA 16x16x32, fused log-softmax stats partials
//     (never materializes 165 MB of logits).
// ---------------------------------------------------------------------------

typedef _Float16 f16;
typedef _Float16 f16x2 __attribute__((ext_vector_type(2)));
typedef _Float16 f16x8 __attribute__((ext_vector_type(8)));
typedef float f32x4 __attribute__((ext_vector_type(4)));

#define SOS_ID 9999
#define NB 32
#define NTT 512      // T
#define NE 512       // eprojs
#define ND 1024      // dunits
#define NA 320       // att_dim
#define NO 10000     // odim
#define NL 129       // L+1 steps
#define NTOK (NL*NB) // 4128
#define GRID_LOOP 640

__device__ __forceinline__ float fdot2f(f16x2 a, f16x2 b, float c) {
#if __has_builtin(__builtin_amdgcn_fdot2)
  return __builtin_amdgcn_fdot2(a, b, c, false);
#else
  return c + (float)a[0]*(float)b[0] + (float)a[1]*(float)b[1];
#endif
}
__device__ __forceinline__ float dot8(f16x8 a, f16x8 b, float acc) {
  acc = fdot2f(__builtin_shufflevector(a, a, 0, 1), __builtin_shufflevector(b, b, 0, 1), acc);
  acc = fdot2f(__builtin_shufflevector(a, a, 2, 3), __builtin_shufflevector(b, b, 2, 3), acc);
  acc = fdot2f(__builtin_shufflevector(a, a, 4, 5), __builtin_shufflevector(b, b, 4, 5), acc);
  acc = fdot2f(__builtin_shufflevector(a, a, 6, 7), __builtin_shufflevector(b, b, 6, 7), acc);
  return acc;
}
__device__ __forceinline__ float sigf(float x) { return 1.0f / (1.0f + __expf(-x)); }
__device__ __forceinline__ float tanhf_fast(float x) { return 1.0f - 2.0f / (1.0f + __expf(2.0f * x)); }

// Monotonic grid barrier: each barrier n waits for count == n*GRID_LOOP.
// No counter reset -> no reset/arrival race. 516 barriers << 2^32.
__device__ __forceinline__ void gbar(unsigned* cnt, unsigned target) {
  __syncthreads();
  __threadfence();
  if (threadIdx.x == 0) {
    __hip_atomic_fetch_add(cnt, 1u, __ATOMIC_RELEASE, __HIP_MEMORY_SCOPE_AGENT);
    while (__hip_atomic_load(cnt, __ATOMIC_ACQUIRE, __HIP_MEMORY_SCOPE_AGENT) < target)
      __builtin_amdgcn_s_sleep(2);
  }
  __threadfence();
  __syncthreads();
}

// ------------------------------ prep kernels -------------------------------
__global__ void k_cvt(const float* __restrict__ s, f16* __restrict__ d, long n) {
  long i = (long)blockIdx.x * 256 + threadIdx.x;
  long st = (long)gridDim.x * 256;
  for (; i < n; i += st) d[i] = (f16)s[i];
}
// W0cat[j][0:1536]=W_ih0[j], [1536:2560]=W_hh0[j]
__global__ void k_w0cat(const float* __restrict__ wih, const float* __restrict__ whh, f16* __restrict__ dst) {
  int j = blockIdx.y; int k = blockIdx.x * 256 + threadIdx.x;
  float v = (k < 1536) ? wih[(long)j * 1536 + k] : whh[(long)j * 1024 + (k - 1536)];
  dst[(long)j * 2560 + k] = (f16)v;
}
// W1cat[j][0:1024]=W_ih1[j], [1024:2048]=W_hh1[j]
__global__ void k_w1cat(const float* __restrict__ wih, const float* __restrict__ whh, f16* __restrict__ dst) {
  int j = blockIdx.y; int k = blockIdx.x * 256 + threadIdx.x;
  float v = (k < 1024) ? wih[(long)j * 1024 + k] : whh[(long)j * 1024 + (k - 1024)];
  dst[(long)j * 2048 + k] = (f16)v;
}
__global__ void k_eys(const int* __restrict__ ys, const float* __restrict__ emb, f16* __restrict__ eys) {
  int sb = blockIdx.y; int k = blockIdx.x * 256 + threadIdx.x;
  int s = sb >> 5, b = sb & 31;
  int tok = (s == 0) ? SOS_ID : ys[b * 128 + (s - 1)];
  eys[(long)sb * 1024 + k] = (f16)emb[(long)tok * 1024 + k];
}
// pre_enc = tanh(hs @ Wenc^T + benc), f16 out
__global__ void k_pre(const f16* __restrict__ hs, const f16* __restrict__ wenc,
                      const float* __restrict__ benc, f16* __restrict__ pre) {
  const int row0 = blockIdx.x * 32;
  for (int idx = threadIdx.x; idx < 32 * NA; idx += 256) {
    int r = row0 + idx / NA, a = idx % NA;
    const f16x8* hp = (const f16x8*)(hs + (long)r * NE);
    const f16x8* wp = (const f16x8*)(wenc + (long)a * NE);
    float acc = 0.f;
#pragma unroll 4
    for (int k = 0; k < 64; ++k) acc = dot8(hp[k], wp[k], acc);
    pre[(long)r * NA + a] = (f16)tanhf_fast(acc + benc[a]);
  }
}
__global__ void k_zero(float* dec, f16* z0h, float* c0, float* c1, f16* zbuf0,
                       float* scal, unsigned* bar) {
  int i = blockIdx.x * 256 + threadIdx.x;
  if (i < 32 * NA) dec[i] = 0.f;
  if (i < NB * ND) { z0h[i] = (f16)0.f; zbuf0[i] = (f16)0.f; }
  if (i < 2 * NB * ND) { c0[i] = 0.f; c1[i] = 0.f; }
  if (i < 8) { scal[i] = 0.f; bar[i] = 0u; }
}

// ------------------------------ persistent loop ----------------------------
struct LoopP {
  const f16 *pre, *hs, *eys, *w0, *w1, *wdec;
  const float *bih0, *bhh0, *bih1, *bhh1;
  const int* hlens;
  float *dec, *ebuf, *emax, *g0, *g1, *c0, *c1;
  f16 *att, *z0h, *zbuf;
  unsigned* bar;
};

// z0(s) from gates0(s) + c0(s-1); c0 parity: c0(k) lives in buf[k&1]
__device__ __forceinline__ float z0_of(const LoopP& p, int s, int b, int h, float* cn_out) {
  float gi = p.g0[b * 4096 + h]        + p.bih0[h]        + p.bhh0[h];
  float gf = p.g0[b * 4096 + 1024 + h] + p.bih0[1024 + h] + p.bhh0[1024 + h];
  float gv = p.g0[b * 4096 + 2048 + h] + p.bih0[2048 + h] + p.bhh0[2048 + h];
  float go = p.g0[b * 4096 + 3072 + h] + p.bih0[3072 + h] + p.bhh0[3072 + h];
  float cold = p.c0[((s + 1) & 1) * (NB * ND) + b * ND + h];
  float cn = sigf(gf) * cold + sigf(gi) * tanhf_fast(gv);
  if (cn_out) *cn_out = cn;
  return sigf(go) * tanhf_fast(cn);
}

__global__ void __launch_bounds__(256, 3) k_loop(LoopP p) {
  __shared__ __align__(16) char lds_raw[33280];
  const int bid = blockIdx.x, tid = threadIdx.x;
  unsigned bcount = 0;

  for (int s = 0; s <= NL; ++s) {
    // ===== P1: e = pre_enc . dec (+ partial max); commit z1(s-1); zero g0 ====
    if (s < NL && bid < 512) {
      const int b = bid >> 4, tc = bid & 15;
      const int hlen = p.hlens[b];
      const int wid = tid >> 6, lane = tid & 63;
      const int t = tc * 32 + wid * 8 + (lane >> 3);
      const int asub = lane & 7;
      const f16x8* pp = (const f16x8*)(p.pre + ((long)(b * NTT + t)) * NA + asub * 40);
      const float4* dp = (const float4*)(p.dec + b * NA + asub * 40);
      float acc = 0.f;
#pragma unroll
      for (int i = 0; i < 5; ++i) {
        f16x8 v = pp[i];
        float4 d0 = dp[2 * i], d1 = dp[2 * i + 1];
        acc += (float)v[0] * d0.x + (float)v[1] * d0.y + (float)v[2] * d0.z + (float)v[3] * d0.w
             + (float)v[4] * d1.x + (float)v[5] * d1.y + (float)v[6] * d1.z + (float)v[7] * d1.w;
      }
      acc += __shfl_xor(acc, 1); acc += __shfl_xor(acc, 2); acc += __shfl_xor(acc, 4);
      float se = 2.0f * acc;  // SCALING
      if (asub == 0) p.ebuf[b * NTT + t] = se;
      float lm = (t < hlen) ? se : -1e30f;
      float* red = (float*)lds_raw;
      red[tid] = lm; __syncthreads();
      for (int st = 128; st > 0; st >>= 1) {
        if (tid < st) red[tid] = fmaxf(red[tid], red[tid + st]);
        __syncthreads();
      }
      if (tid == 0) p.emax[b * 16 + tc] = red[0];
    } else if (bid >= 512 && bid < 544) {
      if (s > 0) {  // commit z1(s-1) -> zbuf[s]; c1(s-1) -> buf[(s-1)&1]
        const int b = bid - 512;
        for (int j = tid; j < ND; j += 256) {
          float gi = p.g1[b * 4096 + j]        + p.bih1[j]        + p.bhh1[j];
          float gf = p.g1[b * 4096 + 1024 + j] + p.bih1[1024 + j] + p.bhh1[1024 + j];
          float gv = p.g1[b * 4096 + 2048 + j] + p.bih1[2048 + j] + p.bhh1[2048 + j];
          float go = p.g1[b * 4096 + 3072 + j] + p.bih1[3072 + j] + p.bhh1[3072 + j];
          float cold = p.c1[(s & 1) * (NB * ND) + b * ND + j];  // c1(s-2)
          float cn = sigf(gf) * cold + sigf(gi) * tanhf_fast(gv);
          p.c1[((s - 1) & 1) * (NB * ND) + b * ND + j] = cn;
          p.zbuf[(long)s * (NB * ND) + b * ND + j] = (f16)(sigf(go) * tanhf_fast(cn));
        }
      }
    } else if (bid >= 544 && s < NL) {
      for (int i = (bid - 544) * 256 + tid; i < NB * 4096; i += 96 * 256) p.g0[i] = 0.f;
    }
    if (s == NL) break;
    gbar(p.bar, ++bcount * GRID_LOOP);

    // ===== P2: softmax + att_c; zero g1 ====================================
    if (bid < 512) {
      float* wbuf = (float*)lds_raw;   // [512]
      float* red = wbuf + 512;         // [256]
      const int b = bid >> 4, dc = bid & 15;
      const int hlen = p.hlens[b];
      float M = -1e30f;
#pragma unroll
      for (int i = 0; i < 16; ++i) M = fmaxf(M, p.emax[b * 16 + i]);
      float ls = 0.f;
      for (int t = tid; t < NTT; t += 256) {
        float w = (t < hlen) ? __expf(p.ebuf[b * NTT + t] - M) : 0.f;
        wbuf[t] = w; ls += w;
      }
      red[tid] = ls; __syncthreads();
      for (int st = 128; st > 0; st >>= 1) {
        if (tid < st) red[tid] += red[tid + st];
        __syncthreads();
      }
      const float inv = 1.0f / red[0];
      __syncthreads();
      const int d = tid & 31, tsub = tid >> 5;
      const f16* hp = p.hs + (long)b * NTT * NE + dc * 32 + d;
      float a = 0.f;
      for (int t = tsub; t < NTT; t += 8) a += wbuf[t] * (float)hp[(long)t * NE];
      red[tsub * 32 + d] = a; __syncthreads();
      if (tid < 32) {
        float s4 = 0.f;
#pragma unroll
        for (int i = 0; i < 8; ++i) s4 += red[i * 32 + tid];
        p.att[b * NE + dc * 32 + tid] = (f16)(s4 * inv);
      }
    } else {
      for (int i = (bid - 512) * 256 + tid; i < NB * 4096; i += 128 * 256) p.g1[i] = 0.f;
    }
    gbar(p.bar, ++bcount * GRID_LOOP);

    // ===== P3: gates0 = [ey|att|z0prev] @ W0cat^T (atomic k-split) =========
    {
      f16* xs = (f16*)lds_raw;  // [32][520] padded (+8 -> bank spread)
      const int jc = bid / 5, kc = bid % 5;
      const int j0 = jc * 32, k0 = kc * 512;
      const f16* src; int rstride;
      if (kc < 2)       { src = p.eys + (long)s * (NB * ND) + k0; rstride = ND; }
      else if (kc == 2) { src = p.att;                            rstride = NE; }
      else              { src = p.z0h + (k0 - 1536);              rstride = ND; }
      for (int i = tid; i < 2048; i += 256) {
        int b = i >> 6, io = (i & 63) << 3;
        *(f16x8*)(xs + b * 520 + io) = *(const f16x8*)(src + (long)b * rstride + io);
      }
      __syncthreads();
      const int b = tid >> 3, jsub = tid & 7;
      const int j = j0 + jsub * 4;
      const f16* wb = p.w0 + (long)j * 2560 + k0;
      const f16x8* xp = (const f16x8*)(xs + b * 520);
      const f16x8* w0p = (const f16x8*)(wb);
      const f16x8* w1p = (const f16x8*)(wb + 2560);
      const f16x8* w2p = (const f16x8*)(wb + 5120);
      const f16x8* w3p = (const f16x8*)(wb + 7680);
      float a0 = 0.f, a1 = 0.f, a2 = 0.f, a3 = 0.f;
#pragma unroll 4
      for (int k = 0; k < 64; ++k) {
        f16x8 xv = xp[k];
        a0 = dot8(xv, w0p[k], a0);
        a1 = dot8(xv, w1p[k], a1);
        a2 = dot8(xv, w2p[k], a2);
        a3 = dot8(xv, w3p[k], a3);
      }
      atomicAdd(&p.g0[b * 4096 + j],     a0);
      atomicAdd(&p.g0[b * 4096 + j + 1], a1);
      atomicAdd(&p.g0[b * 4096 + j + 2], a2);
      atomicAdd(&p.g0[b * 4096 + j + 3], a3);
    }
    gbar(p.bar, ++bcount * GRID_LOOP);

    // ===== P4: gates1 = [z0new|z1prev] @ W1cat^T; commit z0/c0; dec(s+1) ====
    if (bid < 512) {
      f16* xs = (f16*)lds_raw;
      const int jc = bid >> 2, kc = bid & 3;
      const int j0 = jc * 32, k0 = kc * 512;
      if (kc < 2) {  // recompute z0(s) slice (redundant, cheap elementwise)
        for (int i = tid; i < 32 * 512; i += 256) {
          int b = i >> 9, hh = i & 511;
          xs[b * 520 + hh] = (f16)z0_of(p, s, b, k0 + hh, nullptr);
        }
      } else {       // z1(s-1) = zbuf[s]
        const f16* src = p.zbuf + (long)s * (NB * ND) + (k0 - 1024);
        for (int i = tid; i < 2048; i += 256) {
          int b = i >> 6, io = (i & 63) << 3;
          *(f16x8*)(xs + b * 520 + io) = *(const f16x8*)(src + (long)b * 1024 + io);
        }
      }
      __syncthreads();
      const int b = tid >> 3, jsub = tid & 7;
      const int j = j0 + jsub * 4;
      const f16* wb = p.w1 + (long)j * 2048 + k0;
      const f16x8* xp = (const f16x8*)(xs + b * 520);
      const f16x8* w0p = (const f16x8*)(wb);
      const f16x8* w1p = (const f16x8*)(wb + 2048);
      const f16x8* w2p = (const f16x8*)(wb + 4096);
      const f16x8* w3p = (const f16x8*)(wb + 6144);
      float a0 = 0.f, a1 = 0.f, a2 = 0.f, a3 = 0.f;
#pragma unroll 4
      for (int k = 0; k < 64; ++k) {
        f16x8 xv = xp[k];
        a0 = dot8(xv, w0p[k], a0);
        a1 = dot8(xv, w1p[k], a1);
        a2 = dot8(xv, w2p[k], a2);
        a3 = dot8(xv, w3p[k], a3);
      }
      atomicAdd(&p.g1[b * 4096 + j],     a0);
      atomicAdd(&p.g1[b * 4096 + j + 1], a1);
      atomicAdd(&p.g1[b * 4096 + j + 2], a2);
      atomicAdd(&p.g1[b * 4096 + j + 3], a3);
    } else if (bid < 544) {  // commit z0(s) (f16) + c0(s) (buf[s&1])
      const int b = bid - 512;
      for (int h = tid; h < ND; h += 256) {
        float cn;
        float zn = z0_of(p, s, b, h, &cn);
        p.c0[(s & 1) * (NB * ND) + b * ND + h] = cn;
        p.z0h[b * ND + h] = (f16)zn;
      }
    } else if (bid < 576) {  // dec(s+1)[b] = tanh(z0(s) @ Wdec^T)
      const int b = bid - 544;
      f16x2* zd = (f16x2*)lds_raw;  // [512]
      for (int i = tid; i < 512; i += 256) {
        float za = z0_of(p, s, b, 2 * i, nullptr);
        float zb = z0_of(p, s, b, 2 * i + 1, nullptr);
        f16x2 zz = { (f16)za, (f16)zb };
        zd[i] = zz;
      }
      __syncthreads();
      if (tid < 80) {
        const int a0i = tid * 4;
        const f16x2* wp = (const f16x2*)(p.wdec + (long)a0i * 1024);
        float q0 = 0.f, q1 = 0.f, q2 = 0.f, q3 = 0.f;
        for (int k = 0; k < 512; ++k) {
          f16x2 zv = zd[k];
          q0 = fdot2f(zv, wp[k], q0);
          q1 = fdot2f(zv, wp[512 + k], q1);
          q2 = fdot2f(zv, wp[1024 + k], q2);
          q3 = fdot2f(zv, wp[1536 + k], q3);
        }
        p.dec[b * NA + a0i]     = tanhf_fast(q0);
        p.dec[b * NA + a0i + 1] = tanhf_fast(q1);
        p.dec[b * NA + a0i + 2] = tanhf_fast(q2);
        p.dec[b * NA + a0i + 3] = tanhf_fast(q3);
      }
    }
    gbar(p.bar, ++bcount * GRID_LOOP);
  }
}

// ------------------------- logits GEMM + fused CE stats --------------------
// block: 32 m x 512 n; 4 waves, each 32m x 128n (2 A-tiles x 8 B-tiles MFMA).
// Emits per-(row, 128-col stripe) partials {max, sumexp, argmaxval, argmaxidx}.
__global__ void __launch_bounds__(256) k_lgemm(const f16* __restrict__ z, const f16* __restrict__ wout,
                                               const float* __restrict__ bout, float4* __restrict__ part) {
  const int mb = blockIdx.x, nb = blockIdx.y;
  const int wid = threadIdx.x >> 6, lane = threadIdx.x & 63;
  const int lr = lane & 15, lq = lane >> 4;
  const int m0 = mb * 32;
  const int n0 = nb * 512 + wid * 128;
  const f16* arow0 = z + (long)(m0 + lr) * 1024 + lq * 8;
  const f16* arow1 = arow0 + (long)16 * 1024;
  const f16* bp[8];
  int cols[8];
#pragma unroll
  for (int nt = 0; nt < 8; ++nt) {
    int n = n0 + nt * 16 + lr;
    cols[nt] = n;
    int nc = (n < NO) ? n : (NO - 1);  // clamp: no OOB; masked at stats
    bp[nt] = wout + (long)nc * 1024 + lq * 8;
  }
  f32x4 acc[16];
#pragma unroll
  for (int i = 0; i < 16; ++i) acc[i] = (f32x4){0.f, 0.f, 0.f, 0.f};
  for (int kk = 0; kk < 1024; kk += 32) {
    f16x8 a0v = *(const f16x8*)(arow0 + kk);
    f16x8 a1v = *(const f16x8*)(arow1 + kk);
#pragma unroll
    for (int nt = 0; nt < 8; ++nt) {
      f16x8 bv = *(const f16x8*)(bp[nt] + kk);
      acc[nt]     = __builtin_amdgcn_mfma_f32_16x16x32_f16(a0v, bv, acc[nt], 0, 0, 0);
      acc[8 + nt] = __builtin_amdgcn_mfma_f32_16x16x32_f16(a1v, bv, acc[8 + nt], 0, 0, 0);
    }
  }
  float bias[8];
#pragma unroll
  for (int nt = 0; nt < 8; ++nt) bias[nt] = (cols[nt] < NO) ? bout[cols[nt]] : 0.f;
  const int chunk = nb * 4 + wid;
#pragma unroll
  for (int mt = 0; mt < 2; ++mt) {
#pragma unroll
    for (int reg = 0; reg < 4; ++reg) {
      float vals[8];
      float mx = -1e30f, av = -1e30f; int ai = 0;
#pragma unroll
      for (int nt = 0; nt < 8; ++nt) {
        float v = (cols[nt] < NO) ? (acc[mt * 8 + nt][reg] + bias[nt]) : -1e30f;
        vals[nt] = v;
        mx = fmaxf(mx, v);
        if (v > av) { av = v; ai = cols[nt]; }
      }
      float sum = 0.f;
#pragma unroll
      for (int nt = 0; nt < 8; ++nt) sum += (vals[nt] > -9e29f) ? __expf(vals[nt] - mx) : 0.f;
#pragma unroll
      for (int off = 1; off < 16; off <<= 1) {  // merge across the 16-lane quad group
        float mo = __shfl_xor(mx, off);
        float so = __shfl_xor(sum, off);
        float avo = __shfl_xor(av, off);
        int aio = __shfl_xor(ai, off);
        float nm = fmaxf(mx, mo);
        float e1 = (mx > -9e29f) ? __expf(mx - nm) : 0.f;
        float e2 = (mo > -9e29f) ? __expf(mo - nm) : 0.f;
        sum = sum * e1 + so * e2;
        mx = nm;
        if (avo > av || (avo == av && aio < ai)) { av = avo; ai = aio; }
      }
      if (lr == 0) {
        int rowg = m0 + mt * 16 + lq * 4 + reg;
        float4 q; q.x = mx; q.y = sum; q.z = av; q.w = __int_as_float(ai);
        part[(long)rowg * 80 + chunk] = q;
      }
    }
  }
}

// target logit per token (separate tiny dot; same f16 data)
__global__ void k_tl(const f16* __restrict__ z, const f16* __restrict__ wout,
                     const float* __restrict__ bout, const int* __restrict__ ys, float* __restrict__ tl) {
  const int tok = blockIdx.x * 4 + (threadIdx.x >> 6);
  const int lane = threadIdx.x & 63;
  if (tok >= NTOK) return;
  const int s = tok >> 5, b = tok & 31;
  const int tgt = (s < 128) ? ys[b * 128 + s] : SOS_ID;
  const f16x8* zp = (const f16x8*)(z + (long)tok * 1024);
  const f16x8* wp = (const f16x8*)(wout + (long)tgt * 1024);
  float acc = 0.f;
  acc = dot8(zp[lane], wp[lane], acc);
  acc = dot8(zp[64 + lane], wp[64 + lane], acc);
#pragma unroll
  for (int off = 32; off > 0; off >>= 1) acc += __shfl_xor(acc, off);
  if (lane == 0) tl[tok] = acc + bout[tgt];
}

__global__ void k_ce(const float4* __restrict__ part, const float* __restrict__ tl,
                     const int* __restrict__ ys, float* scal) {
  const int m = blockIdx.x * 256 + threadIdx.x;
  float nll = 0.f, okf = 0.f;
  if (m < NTOK) {
    float M = -1e30f, S = 0.f, av = -1e30f; int ai = 0;
    for (int c = 0; c < 80; ++c) {
      float4 q = part[(long)m * 80 + c];
      float qm = q.x, qs = q.y, qa = q.z; int qi = __float_as_int(q.w);
      float nm = fmaxf(M, qm);
      float e1 = (M > -9e29f) ? __expf(M - nm) : 0.f;
      float e2 = (qm > -9e29f) ? __expf(qm - nm) : 0.f;
      S = S * e1 + qs * e2; M = nm;
      if (qa > av || (qa == av && qi < ai)) { av = qa; ai = qi; }
    }
    float lse = M + __logf(S);
    int s = m >> 5, b = m & 31;
    int tgt = (s < 128) ? ys[b * 128 + s] : SOS_ID;
    nll = lse - tl[m];
    okf = (ai == tgt) ? 1.f : 0.f;
  }
  __shared__ float r1[256], r2[256];
  r1[threadIdx.x] = nll; r2[threadIdx.x] = okf; __syncthreads();
  for (int st = 128; st > 0; st >>= 1) {
    if (threadIdx.x < st) { r1[threadIdx.x] += r1[threadIdx.x + st]; r2[threadIdx.x] += r2[threadIdx.x + st]; }
    __syncthreads();
  }
  if (threadIdx.x == 0) { atomicAdd(&scal[0], r1[0]); atomicAdd(&scal[1], r2[0]); }
}

__global__ void k_final(const float* scal, float* out) {
  if (threadIdx.x == 0) {
    float loss = scal[0] * (128.f / 4128.f);
    out[0] = loss;
    out[1] = scal[1] * (1.f / 4128.f);
    out[2] = expf(loss / 32.f);
  }
}

// --------------------------------- launch ----------------------------------
extern "C" void kernel_launch(void* const* d_in, const int* in_sizes, int n_in,
                              void* d_out, int out_size, void* d_ws, size_t ws_size,
                              hipStream_t stream) {
  const float* hs_pad = (const float*)d_in[0];
  const int* hlens    = (const int*)d_in[1];
  const int* ys_pad   = (const int*)d_in[2];
  const float* embed  = (const float*)d_in[3];
  const float* Wenc   = (const float*)d_in[4];
  const float* benc   = (const float*)d_in[5];
  const float* Wdec   = (const float*)d_in[6];
  const float* Wih0   = (const float*)d_in[7];
  const float* Whh0   = (const float*)d_in[8];
  const float* bih0   = (const float*)d_in[9];
  const float* bhh0   = (const float*)d_in[10];
  const float* Wih1   = (const float*)d_in[11];
  const float* Whh1   = (const float*)d_in[12];
  const float* bih1   = (const float*)d_in[13];
  const float* bhh1   = (const float*)d_in[14];
  const float* Wout   = (const float*)d_in[15];
  const float* bout   = (const float*)d_in[16];
  float* out = (float*)d_out;
  (void)in_sizes; (void)n_in; (void)out_size; (void)ws_size;

  char* ws = (char*)d_ws;
  size_t off = 0;
  auto alloc = [&](size_t bytes) -> char* {
    char* pp = ws + off;
    off = (off + bytes + 255) & ~(size_t)255;
    return pp;
  };
  f16* hs16    = (f16*)alloc((size_t)NB * NTT * NE * 2);   // 16.8 MB
  f16* pre16   = (f16*)alloc((size_t)NB * NTT * NA * 2);   // 10.5 MB
  f16* eys16   = (f16*)alloc((size_t)NL * NB * ND * 2);    // 8.45 MB
  f16* w0cat   = (f16*)alloc((size_t)4096 * 2560 * 2);     // 21 MB
  f16* w1cat   = (f16*)alloc((size_t)4096 * 2048 * 2);     // 16.8 MB
  f16* wdec16  = (f16*)alloc((size_t)NA * ND * 2);
  f16* wenc16  = (f16*)alloc((size_t)NA * NE * 2);
  f16* wout16  = (f16*)alloc((size_t)NO * ND * 2);         // 20.5 MB
  f16* zbuf    = (f16*)alloc((size_t)(NL + 1) * NB * ND * 2); // 8.5 MB
  f16* z0h     = (f16*)alloc((size_t)NB * ND * 2);
  float* c0    = (float*)alloc((size_t)2 * NB * ND * 4);
  float* c1    = (float*)alloc((size_t)2 * NB * ND * 4);
  float* dec   = (float*)alloc((size_t)NB * NA * 4);
  float* ebuf  = (float*)alloc((size_t)NB * NTT * 4);
  float* emax  = (float*)alloc((size_t)NB * 16 * 4);
  f16* att16   = (f16*)alloc((size_t)NB * NE * 2);
  float* g0    = (float*)alloc((size_t)NB * 4096 * 4);
  float* g1    = (float*)alloc((size_t)NB * 4096 * 4);
  float* tl    = (float*)alloc((size_t)NTOK * 4);
  float4* part = (float4*)alloc((size_t)NTOK * 80 * 16);   // 5.3 MB
  float* scal  = (float*)alloc(256);
  unsigned* bar = (unsigned*)alloc(256);

  // prep
  k_cvt<<<dim3(2048), dim3(256), 0, stream>>>(hs_pad, hs16, (long)NB * NTT * NE);
  k_cvt<<<dim3(256), dim3(256), 0, stream>>>(Wdec, wdec16, (long)NA * ND);
  k_cvt<<<dim3(128), dim3(256), 0, stream>>>(Wenc, wenc16, (long)NA * NE);
  k_cvt<<<dim3(2048), dim3(256), 0, stream>>>(Wout, wout16, (long)NO * ND);
  k_w0cat<<<dim3(10, 4096), dim3(256), 0, stream>>>(Wih0, Whh0, w0cat);
  k_w1cat<<<dim3(8, 4096), dim3(256), 0, stream>>>(Wih1, Whh1, w1cat);
  k_eys<<<dim3(4, NL * NB), dim3(256), 0, stream>>>(ys_pad, embed, eys16);
  k_pre<<<dim3(512), dim3(256), 0, stream>>>(hs16, wenc16, benc, pre16);
  k_zero<<<dim3(256), dim3(256), 0, stream>>>(dec, z0h, c0, c1, zbuf, scal, bar);

  // recurrent scan (persistent kernel, custom grid barrier)
  LoopP lp;
  lp.pre = pre16; lp.hs = hs16; lp.eys = eys16; lp.w0 = w0cat; lp.w1 = w1cat; lp.wdec = wdec16;
  lp.bih0 = bih0; lp.bhh0 = bhh0; lp.bih1 = bih1; lp.bhh1 = bhh1;
  lp.hlens = hlens;
  lp.dec = dec; lp.ebuf = ebuf; lp.emax = emax; lp.g0 = g0; lp.g1 = g1; lp.c0 = c0; lp.c1 = c1;
  lp.att = att16; lp.z0h = z0h; lp.zbuf = zbuf; lp.bar = bar;
  k_loop<<<dim3(GRID_LOOP), dim3(256), 0, stream>>>(lp);

  // logits + CE (zbuf rows 32.. are the 4128 output states, token m = s*32+b)
  const f16* zrows = zbuf + (size_t)NB * ND;
  k_tl<<<dim3(NTOK / 4), dim3(256), 0, stream>>>(zrows, wout16, bout, ys_pad, tl);
  k_lgemm<<<dim3(129, 20), dim3(256), 0, stream>>>(zrows, wout16, bout, part);
  k_ce<<<dim3(17), dim3(256), 0, stream>>>(part, tl, ys_pad, scal);
  k_final<<<dim3(1), dim3(64), 0, stream>>>(scal, out);
}

// Round 2
// 61479.889 us; speedup vs baseline: 3.1440x; 3.1440x over previous
//
#include <hip/hip_runtime.h>
#include <hip/hip_fp16.h>
#include <math.h>

// ---------------------------------------------------------------------------
// Decoder (ESPnet AttDot + 2x LSTMCell + CE) on gfx950.
// B=32 T=512 EPROJS=512 DUNITS=1024 ATT_DIM=320 ODIM=10000 L=128 (129 steps)
// R1 -> R2: barrier fix. The R1 spin used ACQUIRE loads at agent scope, which
// emit buffer_inv (L1+L2 invalidate) on EVERY poll iteration -> device-wide
// cache thrash while laggards compute -> 219 ms, VALUBusy 1.6%. Now: RELAXED
// polls (agent-scope atomics bypass incoherent caches; no invalidate needed
// for visibility of the counter) + ONE acquire fence per barrier after exit.
// ---------------------------------------------------------------------------

typedef _Float16 f16;
typedef _Float16 f16x2 __attribute__((ext_vector_type(2)));
typedef _Float16 f16x8 __attribute__((ext_vector_type(8)));
typedef float f32x4 __attribute__((ext_vector_type(4)));

#define SOS_ID 9999
#define NB 32
#define NTT 512      // T
#define NE 512       // eprojs
#define ND 1024      // dunits
#define NA 320       // att_dim
#define NO 10000     // odim
#define NL 129       // L+1 steps
#define NTOK (NL*NB) // 4128
#define GRID_LOOP 640

__device__ __forceinline__ float fdot2f(f16x2 a, f16x2 b, float c) {
#if __has_builtin(__builtin_amdgcn_fdot2)
  return __builtin_amdgcn_fdot2(a, b, c, false);
#else
  return c + (float)a[0]*(float)b[0] + (float)a[1]*(float)b[1];
#endif
}
__device__ __forceinline__ float dot8(f16x8 a, f16x8 b, float acc) {
  acc = fdot2f(__builtin_shufflevector(a, a, 0, 1), __builtin_shufflevector(b, b, 0, 1), acc);
  acc = fdot2f(__builtin_shufflevector(a, a, 2, 3), __builtin_shufflevector(b, b, 2, 3), acc);
  acc = fdot2f(__builtin_shufflevector(a, a, 4, 5), __builtin_shufflevector(b, b, 4, 5), acc);
  acc = fdot2f(__builtin_shufflevector(a, a, 6, 7), __builtin_shufflevector(b, b, 6, 7), acc);
  return acc;
}
__device__ __forceinline__ float sigf(float x) { return 1.0f / (1.0f + __expf(-x)); }
__device__ __forceinline__ float tanhf_fast(float x) { return 1.0f - 2.0f / (1.0f + __expf(2.0f * x)); }

// Monotonic grid barrier: barrier n waits for count == n*GRID_LOOP (no reset,
// no ABA). RELAXED polls (no per-poll invalidate!); one RELEASE on arrival
// (buffer_wbl2: push this XCD's dirty L2 lines to the coherent point) and one
// ACQUIRE fence on exit (single buffer_inv so subsequent reads see remote data).
__device__ __forceinline__ void gbar(unsigned* cnt, unsigned target) {
  __syncthreads();   // compiler drains vmcnt here -> block's stores are in L2
  if (threadIdx.x == 0) {
    __hip_atomic_fetch_add(cnt, 1u, __ATOMIC_RELEASE, __HIP_MEMORY_SCOPE_AGENT);
    while (__hip_atomic_load(cnt, __ATOMIC_RELAXED, __HIP_MEMORY_SCOPE_AGENT) < target)
      __builtin_amdgcn_s_sleep(1);
    __builtin_amdgcn_fence(__ATOMIC_ACQUIRE, "agent");  // one L1/L2 invalidate
  }
  __syncthreads();
}

// ------------------------------ prep kernels -------------------------------
__global__ void k_cvt(const float* __restrict__ s, f16* __restrict__ d, long n) {
  long i = (long)blockIdx.x * 256 + threadIdx.x;
  long st = (long)gridDim.x * 256;
  for (; i < n; i += st) d[i] = (f16)s[i];
}
// W0cat[j][0:1536]=W_ih0[j], [1536:2560]=W_hh0[j]
__global__ void k_w0cat(const float* __restrict__ wih, const float* __restrict__ whh, f16* __restrict__ dst) {
  int j = blockIdx.y; int k = blockIdx.x * 256 + threadIdx.x;
  float v = (k < 1536) ? wih[(long)j * 1536 + k] : whh[(long)j * 1024 + (k - 1536)];
  dst[(long)j * 2560 + k] = (f16)v;
}
// W1cat[j][0:1024]=W_ih1[j], [1024:2048]=W_hh1[j]
__global__ void k_w1cat(const float* __restrict__ wih, const float* __restrict__ whh, f16* __restrict__ dst) {
  int j = blockIdx.y; int k = blockIdx.x * 256 + threadIdx.x;
  float v = (k < 1024) ? wih[(long)j * 1024 + k] : whh[(long)j * 1024 + (k - 1024)];
  dst[(long)j * 2048 + k] = (f16)v;
}
__global__ void k_eys(const int* __restrict__ ys, const float* __restrict__ emb, f16* __restrict__ eys) {
  int sb = blockIdx.y; int k = blockIdx.x * 256 + threadIdx.x;
  int s = sb >> 5, b = sb & 31;
  int tok = (s == 0) ? SOS_ID : ys[b * 128 + (s - 1)];
  eys[(long)sb * 1024 + k] = (f16)emb[(long)tok * 1024 + k];
}
// pre_enc = tanh(hs @ Wenc^T + benc), f16 out
__global__ void k_pre(const f16* __restrict__ hs, const f16* __restrict__ wenc,
                      const float* __restrict__ benc, f16* __restrict__ pre) {
  const int row0 = blockIdx.x * 32;
  for (int idx = threadIdx.x; idx < 32 * NA; idx += 256) {
    int r = row0 + idx / NA, a = idx % NA;
    const f16x8* hp = (const f16x8*)(hs + (long)r * NE);
    const f16x8* wp = (const f16x8*)(wenc + (long)a * NE);
    float acc = 0.f;
#pragma unroll 4
    for (int k = 0; k < 64; ++k) acc = dot8(hp[k], wp[k], acc);
    pre[(long)r * NA + a] = (f16)tanhf_fast(acc + benc[a]);
  }
}
__global__ void k_zero(float* dec, f16* z0h, float* c0, float* c1, f16* zbuf0,
                       float* scal, unsigned* bar) {
  int i = blockIdx.x * 256 + threadIdx.x;
  if (i < 32 * NA) dec[i] = 0.f;
  if (i < NB * ND) { z0h[i] = (f16)0.f; zbuf0[i] = (f16)0.f; }
  if (i < 2 * NB * ND) { c0[i] = 0.f; c1[i] = 0.f; }
  if (i < 8) { scal[i] = 0.f; bar[i] = 0u; }
}

// ------------------------------ persistent loop ----------------------------
struct LoopP {
  const f16 *pre, *hs, *eys, *w0, *w1, *wdec;
  const float *bih0, *bhh0, *bih1, *bhh1;
  const int* hlens;
  float *dec, *ebuf, *emax, *g0, *g1, *c0, *c1;
  f16 *att, *z0h, *zbuf;
  unsigned* bar;
};

// z0(s) from gates0(s) + c0(s-1); c0 parity: c0(k) lives in buf[k&1]
__device__ __forceinline__ float z0_of(const LoopP& p, int s, int b, int h, float* cn_out) {
  float gi = p.g0[b * 4096 + h]        + p.bih0[h]        + p.bhh0[h];
  float gf = p.g0[b * 4096 + 1024 + h] + p.bih0[1024 + h] + p.bhh0[1024 + h];
  float gv = p.g0[b * 4096 + 2048 + h] + p.bih0[2048 + h] + p.bhh0[2048 + h];
  float go = p.g0[b * 4096 + 3072 + h] + p.bih0[3072 + h] + p.bhh0[3072 + h];
  float cold = p.c0[((s + 1) & 1) * (NB * ND) + b * ND + h];
  float cn = sigf(gf) * cold + sigf(gi) * tanhf_fast(gv);
  if (cn_out) *cn_out = cn;
  return sigf(go) * tanhf_fast(cn);
}

__global__ void __launch_bounds__(256, 3) k_loop(LoopP p) {
  __shared__ __align__(16) char lds_raw[33280];
  const int bid = blockIdx.x, tid = threadIdx.x;
  unsigned bcount = 0;

  for (int s = 0; s <= NL; ++s) {
    // ===== P1: e = pre_enc . dec (+ partial max); commit z1(s-1); zero g0 ====
    if (s < NL && bid < 512) {
      const int b = bid >> 4, tc = bid & 15;
      const int hlen = p.hlens[b];
      const int wid = tid >> 6, lane = tid & 63;
      const int t = tc * 32 + wid * 8 + (lane >> 3);
      const int asub = lane & 7;
      const f16x8* pp = (const f16x8*)(p.pre + ((long)(b * NTT + t)) * NA + asub * 40);
      const float4* dp = (const float4*)(p.dec + b * NA + asub * 40);
      float acc = 0.f;
#pragma unroll
      for (int i = 0; i < 5; ++i) {
        f16x8 v = pp[i];
        float4 d0 = dp[2 * i], d1 = dp[2 * i + 1];
        acc += (float)v[0] * d0.x + (float)v[1] * d0.y + (float)v[2] * d0.z + (float)v[3] * d0.w
             + (float)v[4] * d1.x + (float)v[5] * d1.y + (float)v[6] * d1.z + (float)v[7] * d1.w;
      }
      acc += __shfl_xor(acc, 1); acc += __shfl_xor(acc, 2); acc += __shfl_xor(acc, 4);
      float se = 2.0f * acc;  // SCALING
      if (asub == 0) p.ebuf[b * NTT + t] = se;
      float lm = (t < hlen) ? se : -1e30f;
      float* red = (float*)lds_raw;
      red[tid] = lm; __syncthreads();
      for (int st = 128; st > 0; st >>= 1) {
        if (tid < st) red[tid] = fmaxf(red[tid], red[tid + st]);
        __syncthreads();
      }
      if (tid == 0) p.emax[b * 16 + tc] = red[0];
    } else if (bid >= 512 && bid < 544) {
      if (s > 0) {  // commit z1(s-1) -> zbuf[s]; c1(s-1) -> buf[(s-1)&1]
        const int b = bid - 512;
        for (int j = tid; j < ND; j += 256) {
          float gi = p.g1[b * 4096 + j]        + p.bih1[j]        + p.bhh1[j];
          float gf = p.g1[b * 4096 + 1024 + j] + p.bih1[1024 + j] + p.bhh1[1024 + j];
          float gv = p.g1[b * 4096 + 2048 + j] + p.bih1[2048 + j] + p.bhh1[2048 + j];
          float go = p.g1[b * 4096 + 3072 + j] + p.bih1[3072 + j] + p.bhh1[3072 + j];
          float cold = p.c1[(s & 1) * (NB * ND) + b * ND + j];  // c1(s-2)
          float cn = sigf(gf) * cold + sigf(gi) * tanhf_fast(gv);
          p.c1[((s - 1) & 1) * (NB * ND) + b * ND + j] = cn;
          p.zbuf[(long)s * (NB * ND) + b * ND + j] = (f16)(sigf(go) * tanhf_fast(cn));
        }
      }
    } else if (bid >= 544 && s < NL) {
      for (int i = (bid - 544) * 256 + tid; i < NB * 4096; i += 96 * 256) p.g0[i] = 0.f;
    }
    if (s == NL) break;
    gbar(p.bar, ++bcount * GRID_LOOP);

    // ===== P2: softmax + att_c; zero g1 ====================================
    if (bid < 512) {
      float* wbuf = (float*)lds_raw;   // [512]
      float* red = wbuf + 512;         // [256]
      const int b = bid >> 4, dc = bid & 15;
      const int hlen = p.hlens[b];
      float M = -1e30f;
#pragma unroll
      for (int i = 0; i < 16; ++i) M = fmaxf(M, p.emax[b * 16 + i]);
      float ls = 0.f;
      for (int t = tid; t < NTT; t += 256) {
        float w = (t < hlen) ? __expf(p.ebuf[b * NTT + t] - M) : 0.f;
        wbuf[t] = w; ls += w;
      }
      red[tid] = ls; __syncthreads();
      for (int st = 128; st > 0; st >>= 1) {
        if (tid < st) red[tid] += red[tid + st];
        __syncthreads();
      }
      const float inv = 1.0f / red[0];
      __syncthreads();
      const int d = tid & 31, tsub = tid >> 5;
      const f16* hp = p.hs + (long)b * NTT * NE + dc * 32 + d;
      float a = 0.f;
      for (int t = tsub; t < NTT; t += 8) a += wbuf[t] * (float)hp[(long)t * NE];
      red[tsub * 32 + d] = a; __syncthreads();
      if (tid < 32) {
        float s4 = 0.f;
#pragma unroll
        for (int i = 0; i < 8; ++i) s4 += red[i * 32 + tid];
        p.att[b * NE + dc * 32 + tid] = (f16)(s4 * inv);
      }
    } else {
      for (int i = (bid - 512) * 256 + tid; i < NB * 4096; i += 128 * 256) p.g1[i] = 0.f;
    }
    gbar(p.bar, ++bcount * GRID_LOOP);

    // ===== P3: gates0 = [ey|att|z0prev] @ W0cat^T (atomic k-split) =========
    {
      f16* xs = (f16*)lds_raw;  // [32][520] padded (+8 -> bank spread)
      const int jc = bid / 5, kc = bid % 5;
      const int j0 = jc * 32, k0 = kc * 512;
      const f16* src; int rstride;
      if (kc < 2)       { src = p.eys + (long)s * (NB * ND) + k0; rstride = ND; }
      else if (kc == 2) { src = p.att;                            rstride = NE; }
      else              { src = p.z0h + (k0 - 1536);              rstride = ND; }
      for (int i = tid; i < 2048; i += 256) {
        int b = i >> 6, io = (i & 63) << 3;
        *(f16x8*)(xs + b * 520 + io) = *(const f16x8*)(src + (long)b * rstride + io);
      }
      __syncthreads();
      const int b = tid >> 3, jsub = tid & 7;
      const int j = j0 + jsub * 4;
      const f16* wb = p.w0 + (long)j * 2560 + k0;
      const f16x8* xp = (const f16x8*)(xs + b * 520);
      const f16x8* w0p = (const f16x8*)(wb);
      const f16x8* w1p = (const f16x8*)(wb + 2560);
      const f16x8* w2p = (const f16x8*)(wb + 5120);
      const f16x8* w3p = (const f16x8*)(wb + 7680);
      float a0 = 0.f, a1 = 0.f, a2 = 0.f, a3 = 0.f;
#pragma unroll 4
      for (int k = 0; k < 64; ++k) {
        f16x8 xv = xp[k];
        a0 = dot8(xv, w0p[k], a0);
        a1 = dot8(xv, w1p[k], a1);
        a2 = dot8(xv, w2p[k], a2);
        a3 = dot8(xv, w3p[k], a3);
      }
      atomicAdd(&p.g0[b * 4096 + j],     a0);
      atomicAdd(&p.g0[b * 4096 + j + 1], a1);
      atomicAdd(&p.g0[b * 4096 + j + 2], a2);
      atomicAdd(&p.g0[b * 4096 + j + 3], a3);
    }
    gbar(p.bar, ++bcount * GRID_LOOP);

    // ===== P4: gates1 = [z0new|z1prev] @ W1cat^T; commit z0/c0; dec(s+1) ====
    if (bid < 512) {
      f16* xs = (f16*)lds_raw;
      const int jc = bid >> 2, kc = bid & 3;
      const int j0 = jc * 32, k0 = kc * 512;
      if (kc < 2) {  // recompute z0(s) slice (redundant, cheap elementwise)
        for (int i = tid; i < 32 * 512; i += 256) {
          int b = i >> 9, hh = i & 511;
          xs[b * 520 + hh] = (f16)z0_of(p, s, b, k0 + hh, nullptr);
        }
      } else {       // z1(s-1) = zbuf[s]
        const f16* src = p.zbuf + (long)s * (NB * ND) + (k0 - 1024);
        for (int i = tid; i < 2048; i += 256) {
          int b = i >> 6, io = (i & 63) << 3;
          *(f16x8*)(xs + b * 520 + io) = *(const f16x8*)(src + (long)b * 1024 + io);
        }
      }
      __syncthreads();
      const int b = tid >> 3, jsub = tid & 7;
      const int j = j0 + jsub * 4;
      const f16* wb = p.w1 + (long)j * 2048 + k0;
      const f16x8* xp = (const f16x8*)(xs + b * 520);
      const f16x8* w0p = (const f16x8*)(wb);
      const f16x8* w1p = (const f16x8*)(wb + 2048);
      const f16x8* w2p = (const f16x8*)(wb + 4096);
      const f16x8* w3p = (const f16x8*)(wb + 6144);
      float a0 = 0.f, a1 = 0.f, a2 = 0.f, a3 = 0.f;
#pragma unroll 4
      for (int k = 0; k < 64; ++k) {
        f16x8 xv = xp[k];
        a0 = dot8(xv, w0p[k], a0);
        a1 = dot8(xv, w1p[k], a1);
        a2 = dot8(xv, w2p[k], a2);
        a3 = dot8(xv, w3p[k], a3);
      }
      atomicAdd(&p.g1[b * 4096 + j],     a0);
      atomicAdd(&p.g1[b * 4096 + j + 1], a1);
      atomicAdd(&p.g1[b * 4096 + j + 2], a2);
      atomicAdd(&p.g1[b * 4096 + j + 3], a3);
    } else if (bid < 544) {  // commit z0(s) (f16) + c0(s) (buf[s&1])
      const int b = bid - 512;
      for (int h = tid; h < ND; h += 256) {
        float cn;
        float zn = z0_of(p, s, b, h, &cn);
        p.c0[(s & 1) * (NB * ND) + b * ND + h] = cn;
        p.z0h[b * ND + h] = (f16)zn;
      }
    } else if (bid < 576) {  // dec(s+1)[b] = tanh(z0(s) @ Wdec^T)
      const int b = bid - 544;
      f16x2* zd = (f16x2*)lds_raw;  // [512]
      for (int i = tid; i < 512; i += 256) {
        float za = z0_of(p, s, b, 2 * i, nullptr);
        float zb = z0_of(p, s, b, 2 * i + 1, nullptr);
        f16x2 zz = { (f16)za, (f16)zb };
        zd[i] = zz;
      }
      __syncthreads();
      if (tid < 80) {
        const int a0i = tid * 4;
        const f16x2* wp = (const f16x2*)(p.wdec + (long)a0i * 1024);
        float q0 = 0.f, q1 = 0.f, q2 = 0.f, q3 = 0.f;
        for (int k = 0; k < 512; ++k) {
          f16x2 zv = zd[k];
          q0 = fdot2f(zv, wp[k], q0);
          q1 = fdot2f(zv, wp[512 + k], q1);
          q2 = fdot2f(zv, wp[1024 + k], q2);
          q3 = fdot2f(zv, wp[1536 + k], q3);
        }
        p.dec[b * NA + a0i]     = tanhf_fast(q0);
        p.dec[b * NA + a0i + 1] = tanhf_fast(q1);
        p.dec[b * NA + a0i + 2] = tanhf_fast(q2);
        p.dec[b * NA + a0i + 3] = tanhf_fast(q3);
      }
    }
    gbar(p.bar, ++bcount * GRID_LOOP);
  }
}

// ------------------------- logits GEMM + fused CE stats --------------------
// block: 32 m x 512 n; 4 waves, each 32m x 128n (2 A-tiles x 8 B-tiles MFMA).
// Emits per-(row, 128-col stripe) partials {max, sumexp, argmaxval, argmaxidx}.
__global__ void __launch_bounds__(256) k_lgemm(const f16* __restrict__ z, const f16* __restrict__ wout,
                                               const float* __restrict__ bout, float4* __restrict__ part) {
  const int mb = blockIdx.x, nb = blockIdx.y;
  const int wid = threadIdx.x >> 6, lane = threadIdx.x & 63;
  const int lr = lane & 15, lq = lane >> 4;
  const int m0 = mb * 32;
  const int n0 = nb * 512 + wid * 128;
  const f16* arow0 = z + (long)(m0 + lr) * 1024 + lq * 8;
  const f16* arow1 = arow0 + (long)16 * 1024;
  const f16* bp[8];
  int cols[8];
#pragma unroll
  for (int nt = 0; nt < 8; ++nt) {
    int n = n0 + nt * 16 + lr;
    cols[nt] = n;
    int nc = (n < NO) ? n : (NO - 1);  // clamp: no OOB; masked at stats
    bp[nt] = wout + (long)nc * 1024 + lq * 8;
  }
  f32x4 acc[16];
#pragma unroll
  for (int i = 0; i < 16; ++i) acc[i] = (f32x4){0.f, 0.f, 0.f, 0.f};
  for (int kk = 0; kk < 1024; kk += 32) {
    f16x8 a0v = *(const f16x8*)(arow0 + kk);
    f16x8 a1v = *(const f16x8*)(arow1 + kk);
#pragma unroll
    for (int nt = 0; nt < 8; ++nt) {
      f16x8 bv = *(const f16x8*)(bp[nt] + kk);
      acc[nt]     = __builtin_amdgcn_mfma_f32_16x16x32_f16(a0v, bv, acc[nt], 0, 0, 0);
      acc[8 + nt] = __builtin_amdgcn_mfma_f32_16x16x32_f16(a1v, bv, acc[8 + nt], 0, 0, 0);
    }
  }
  float bias[8];
#pragma unroll
  for (int nt = 0; nt < 8; ++nt) bias[nt] = (cols[nt] < NO) ? bout[cols[nt]] : 0.f;
  const int chunk = nb * 4 + wid;
#pragma unroll
  for (int mt = 0; mt < 2; ++mt) {
#pragma unroll
    for (int reg = 0; reg < 4; ++reg) {
      float vals[8];
      float mx = -1e30f, av = -1e30f; int ai = 0;
#pragma unroll
      for (int nt = 0; nt < 8; ++nt) {
        float v = (cols[nt] < NO) ? (acc[mt * 8 + nt][reg] + bias[nt]) : -1e30f;
        vals[nt] = v;
        mx = fmaxf(mx, v);
        if (v > av) { av = v; ai = cols[nt]; }
      }
      float sum = 0.f;
#pragma unroll
      for (int nt = 0; nt < 8; ++nt) sum += (vals[nt] > -9e29f) ? __expf(vals[nt] - mx) : 0.f;
#pragma unroll
      for (int off = 1; off < 16; off <<= 1) {  // merge across the 16-lane quad group
        float mo = __shfl_xor(mx, off);
        float so = __shfl_xor(sum, off);
        float avo = __shfl_xor(av, off);
        int aio = __shfl_xor(ai, off);
        float nm = fmaxf(mx, mo);
        float e1 = (mx > -9e29f) ? __expf(mx - nm) : 0.f;
        float e2 = (mo > -9e29f) ? __expf(mo - nm) : 0.f;
        sum = sum * e1 + so * e2;
        mx = nm;
        if (avo > av || (avo == av && aio < ai)) { av = avo; ai = aio; }
      }
      if (lr == 0) {
        int rowg = m0 + mt * 16 + lq * 4 + reg;
        float4 q; q.x = mx; q.y = sum; q.z = av; q.w = __int_as_float(ai);
        part[(long)rowg * 80 + chunk] = q;
      }
    }
  }
}

// target logit per token (separate tiny dot; same f16 data)
__global__ void k_tl(const f16* __restrict__ z, const f16* __restrict__ wout,
                     const float* __restrict__ bout, const int* __restrict__ ys, float* __restrict__ tl) {
  const int tok = blockIdx.x * 4 + (threadIdx.x >> 6);
  const int lane = threadIdx.x & 63;
  if (tok >= NTOK) return;
  const int s = tok >> 5, b = tok & 31;
  const int tgt = (s < 128) ? ys[b * 128 + s] : SOS_ID;
  const f16x8* zp = (const f16x8*)(z + (long)tok * 1024);
  const f16x8* wp = (const f16x8*)(wout + (long)tgt * 1024);
  float acc = 0.f;
  acc = dot8(zp[lane], wp[lane], acc);
  acc = dot8(zp[64 + lane], wp[64 + lane], acc);
#pragma unroll
  for (int off = 32; off > 0; off >>= 1) acc += __shfl_xor(acc, off);
  if (lane == 0) tl[tok] = acc + bout[tgt];
}

__global__ void k_ce(const float4* __restrict__ part, const float* __restrict__ tl,
                     const int* __restrict__ ys, float* scal) {
  const int m = blockIdx.x * 256 + threadIdx.x;
  float nll = 0.f, okf = 0.f;
  if (m < NTOK) {
    float M = -1e30f, S = 0.f, av = -1e30f; int ai = 0;
    for (int c = 0; c < 80; ++c) {
      float4 q = part[(long)m * 80 + c];
      float qm = q.x, qs = q.y, qa = q.z; int qi = __float_as_int(q.w);
      float nm = fmaxf(M, qm);
      float e1 = (M > -9e29f) ? __expf(M - nm) : 0.f;
      float e2 = (qm > -9e29f) ? __expf(qm - nm) : 0.f;
      S = S * e1 + qs * e2; M = nm;
      if (qa > av || (qa == av && qi < ai)) { av = qa; ai = qi; }
    }
    float lse = M + __logf(S);
    int s = m >> 5, b = m & 31;
    int tgt = (s < 128) ? ys[b * 128 + s] : SOS_ID;
    nll = lse - tl[m];
    okf = (ai == tgt) ? 1.f : 0.f;
  }
  __shared__ float r1[256], r2[256];
  r1[threadIdx.x] = nll; r2[threadIdx.x] = okf; __syncthreads();
  for (int st = 128; st > 0; st >>= 1) {
    if (threadIdx.x < st) { r1[threadIdx.x] += r1[threadIdx.x + st]; r2[threadIdx.x] += r2[threadIdx.x + st]; }
    __syncthreads();
  }
  if (threadIdx.x == 0) { atomicAdd(&scal[0], r1[0]); atomicAdd(&scal[1], r2[0]); }
}

__global__ void k_final(const float* scal, float* out) {
  if (threadIdx.x == 0) {
    float loss = scal[0] * (128.f / 4128.f);
    out[0] = loss;
    out[1] = scal[1] * (1.f / 4128.f);
    out[2] = expf(loss / 32.f);
  }
}

// --------------------------------- launch ----------------------------------
extern "C" void kernel_launch(void* const* d_in, const int* in_sizes, int n_in,
                              void* d_out, int out_size, void* d_ws, size_t ws_size,
                              hipStream_t stream) {
  const float* hs_pad = (const float*)d_in[0];
  const int* hlens    = (const int*)d_in[1];
  const int* ys_pad   = (const int*)d_in[2];
  const float* embed  = (const float*)d_in[3];
  const float* Wenc   = (const float*)d_in[4];
  const float* benc   = (const float*)d_in[5];
  const float* Wdec   = (const float*)d_in[6];
  const float* Wih0   = (const float*)d_in[7];
  const float* Whh0   = (const float*)d_in[8];
  const float* bih0   = (const float*)d_in[9];
  const float* bhh0   = (const float*)d_in[10];
  const float* Wih1   = (const float*)d_in[11];
  const float* Whh1   = (const float*)d_in[12];
  const float* bih1   = (const float*)d_in[13];
  const float* bhh1   = (const float*)d_in[14];
  const float* Wout   = (const float*)d_in[15];
  const float* bout   = (const float*)d_in[16];
  float* out = (float*)d_out;
  (void)in_sizes; (void)n_in; (void)out_size; (void)ws_size;

  char* ws = (char*)d_ws;
  size_t off = 0;
  auto alloc = [&](size_t bytes) -> char* {
    char* pp = ws + off;
    off = (off + bytes + 255) & ~(size_t)255;
    return pp;
  };
  f16* hs16    = (f16*)alloc((size_t)NB * NTT * NE * 2);   // 16.8 MB
  f16* pre16   = (f16*)alloc((size_t)NB * NTT * NA * 2);   // 10.5 MB
  f16* eys16   = (f16*)alloc((size_t)NL * NB * ND * 2);    // 8.45 MB
  f16* w0cat   = (f16*)alloc((size_t)4096 * 2560 * 2);     // 21 MB
  f16* w1cat   = (f16*)alloc((size_t)4096 * 2048 * 2);     // 16.8 MB
  f16* wdec16  = (f16*)alloc((size_t)NA * ND * 2);
  f16* wenc16  = (f16*)alloc((size_t)NA * NE * 2);
  f16* wout16  = (f16*)alloc((size_t)NO * ND * 2);         // 20.5 MB
  f16* zbuf    = (f16*)alloc((size_t)(NL + 1) * NB * ND * 2); // 8.5 MB
  f16* z0h     = (f16*)alloc((size_t)NB * ND * 2);
  float* c0    = (float*)alloc((size_t)2 * NB * ND * 4);
  float* c1    = (float*)alloc((size_t)2 * NB * ND * 4);
  float* dec   = (float*)alloc((size_t)NB * NA * 4);
  float* ebuf  = (float*)alloc((size_t)NB * NTT * 4);
  float* emax  = (float*)alloc((size_t)NB * 16 * 4);
  f16* att16   = (f16*)alloc((size_t)NB * NE * 2);
  float* g0    = (float*)alloc((size_t)NB * 4096 * 4);
  float* g1    = (float*)alloc((size_t)NB * 4096 * 4);
  float* tl    = (float*)alloc((size_t)NTOK * 4);
  float4* part = (float4*)alloc((size_t)NTOK * 80 * 16);   // 5.3 MB
  float* scal  = (float*)alloc(256);
  unsigned* bar = (unsigned*)alloc(256);

  // prep
  k_cvt<<<dim3(2048), dim3(256), 0, stream>>>(hs_pad, hs16, (long)NB * NTT * NE);
  k_cvt<<<dim3(256), dim3(256), 0, stream>>>(Wdec, wdec16, (long)NA * ND);
  k_cvt<<<dim3(128), dim3(256), 0, stream>>>(Wenc, wenc16, (long)NA * NE);
  k_cvt<<<dim3(2048), dim3(256), 0, stream>>>(Wout, wout16, (long)NO * ND);
  k_w0cat<<<dim3(10, 4096), dim3(256), 0, stream>>>(Wih0, Whh0, w0cat);
  k_w1cat<<<dim3(8, 4096), dim3(256), 0, stream>>>(Wih1, Whh1, w1cat);
  k_eys<<<dim3(4, NL * NB), dim3(256), 0, stream>>>(ys_pad, embed, eys16);
  k_pre<<<dim3(512), dim3(256), 0, stream>>>(hs16, wenc16, benc, pre16);
  k_zero<<<dim3(256), dim3(256), 0, stream>>>(dec, z0h, c0, c1, zbuf, scal, bar);

  // recurrent scan (persistent kernel, custom grid barrier)
  LoopP lp;
  lp.pre = pre16; lp.hs = hs16; lp.eys = eys16; lp.w0 = w0cat; lp.w1 = w1cat; lp.wdec = wdec16;
  lp.bih0 = bih0; lp.bhh0 = bhh0; lp.bih1 = bih1; lp.bhh1 = bhh1;
  lp.hlens = hlens;
  lp.dec = dec; lp.ebuf = ebuf; lp.emax = emax; lp.g0 = g0; lp.g1 = g1; lp.c0 = c0; lp.c1 = c1;
  lp.att = att16; lp.z0h = z0h; lp.zbuf = zbuf; lp.bar = bar;
  k_loop<<<dim3(GRID_LOOP), dim3(256), 0, stream>>>(lp);

  // logits + CE (zbuf rows 32.. are the 4128 output states, token m = s*32+b)
  const f16* zrows = zbuf + (size_t)NB * ND;
  k_tl<<<dim3(NTOK / 4), dim3(256), 0, stream>>>(zrows, wout16, bout, ys_pad, tl);
  k_lgemm<<<dim3(129, 20), dim3(256), 0, stream>>>(zrows, wout16, bout, part);
  k_ce<<<dim3(17), dim3(256), 0, stream>>>(part, tl, ys_pad, scal);
  k_final<<<dim3(1), dim3(64), 0, stream>>>(scal, out);
}

// Round 3
// 14495.308 us; speedup vs baseline: 13.3346x; 4.2414x over previous
//
#include <hip/hip_runtime.h>
#include <hip/hip_fp16.h>
#include <math.h>

// ---------------------------------------------------------------------------
// Decoder (ESPnet AttDot + 2x LSTMCell + CE) on gfx950.
// B=32 T=512 EPROJS=512 DUNITS=1024 ATT_DIM=320 ODIM=10000 L=128 (129 steps)
// R2 -> R3: restructured persistent scan.
//  * NO cache invalidates: mutable cross-block data via relaxed agent atomics
//    (coherent, uncached); RO weights stay L2-resident across all 129 steps.
//  * Two-level barrier (8 sub-counters + root + flag, s_sleep backoff).
//  * Ownership: gate-slice blocks hold GEMM partials in REGISTERS across
//    phases; c0/c1 cell state lives in LDS for the whole kernel.
//  * 3 barriers/step: A(att || g0 ey+z0prev || g1 z1prev) -> B(g0 att-part,
//    commit z0) -> C(g1 z0-part, commit z1 || dec(s+1)).
// ---------------------------------------------------------------------------

typedef _Float16 f16;
typedef _Float16 f16x2 __attribute__((ext_vector_type(2)));
typedef _Float16 f16x4 __attribute__((ext_vector_type(4)));
typedef _Float16 f16x8 __attribute__((ext_vector_type(8)));
typedef float f32x4 __attribute__((ext_vector_type(4)));

#define SOS_ID 9999
#define NB 32
#define NTT 512
#define NE 512
#define ND 1024
#define NA 320
#define NO 10000
#define NL 129
#define NTOK (NL*NB)
#define GRID_LOOP 288   // 128 g0 + 128 g1 + 32 att

union PU32 { unsigned u; f16x2 h; };
union PU64 { unsigned long long u; f16x4 h; unsigned w[2]; };

__device__ __forceinline__ float fdot2f(f16x2 a, f16x2 b, float c) {
#if __has_builtin(__builtin_amdgcn_fdot2)
  return __builtin_amdgcn_fdot2(a, b, c, false);
#else
  return c + (float)a[0]*(float)b[0] + (float)a[1]*(float)b[1];
#endif
}
__device__ __forceinline__ float dot4(f16x4 a, f16x4 b, float acc) {
  f16x2 a0 = {a[0], a[1]}, b0 = {b[0], b[1]};
  f16x2 a1 = {a[2], a[3]}, b1 = {b[2], b[3]};
  acc = fdot2f(a0, b0, acc);
  acc = fdot2f(a1, b1, acc);
  return acc;
}
__device__ __forceinline__ float dot8(f16x8 a, f16x8 b, float acc) {
  acc = fdot2f(__builtin_shufflevector(a, a, 0, 1), __builtin_shufflevector(b, b, 0, 1), acc);
  acc = fdot2f(__builtin_shufflevector(a, a, 2, 3), __builtin_shufflevector(b, b, 2, 3), acc);
  acc = fdot2f(__builtin_shufflevector(a, a, 4, 5), __builtin_shufflevector(b, b, 4, 5), acc);
  acc = fdot2f(__builtin_shufflevector(a, a, 6, 7), __builtin_shufflevector(b, b, 6, 7), acc);
  return acc;
}
__device__ __forceinline__ float sigf(float x) { return 1.0f / (1.0f + __expf(-x)); }
__device__ __forceinline__ float tanhf_fast(float x) { return 1.0f - 2.0f / (1.0f + __expf(2.0f * x)); }

__device__ __forceinline__ unsigned long long aload64(const void* p) {
  return __hip_atomic_load((const unsigned long long*)p, __ATOMIC_RELAXED, __HIP_MEMORY_SCOPE_AGENT);
}
__device__ __forceinline__ void astore32(void* p, unsigned v) {
  __hip_atomic_store((unsigned*)p, v, __ATOMIC_RELAXED, __HIP_MEMORY_SCOPE_AGENT);
}
__device__ __forceinline__ unsigned pack2(float a, float b) {
  PU32 u; u.h[0] = (f16)a; u.h[1] = (f16)b; return u.u;
}

// Two-level monotonic barrier. bar[j*32] sub-counters (8), bar[256] root,
// bar[288] flag. No acquire fence (mutable data is atomic-only => no stale
// cache lines to invalidate). Release on arrival orders prior atomic stores.
__device__ __forceinline__ void gbar2(unsigned* bar, int bid, unsigned idx) {
  __syncthreads();
  if (threadIdx.x == 0) {
    unsigned old = __hip_atomic_fetch_add(&bar[(bid & 7) * 32], 1u, __ATOMIC_RELEASE, __HIP_MEMORY_SCOPE_AGENT);
    if (old + 1u == idx * (GRID_LOOP / 8)) {
      unsigned r = __hip_atomic_fetch_add(&bar[256], 1u, __ATOMIC_RELEASE, __HIP_MEMORY_SCOPE_AGENT);
      if (r + 1u == idx * 8u)
        __hip_atomic_store(&bar[288], idx, __ATOMIC_RELEASE, __HIP_MEMORY_SCOPE_AGENT);
    }
    while (__hip_atomic_load(&bar[288], __ATOMIC_RELAXED, __HIP_MEMORY_SCOPE_AGENT) < idx)
      __builtin_amdgcn_s_sleep(16);
  }
  __syncthreads();
  asm volatile("" ::: "memory");
}

// ------------------------------ prep kernels -------------------------------
__global__ void k_cvt(const float* __restrict__ s, f16* __restrict__ d, long n) {
  long i = (long)blockIdx.x * 256 + threadIdx.x;
  long st = (long)gridDim.x * 256;
  for (; i < n; i += st) d[i] = (f16)s[i];
}
// w0cat cols: [0:1024)=Wih0 ey part, [1024:2048)=Whh0 (z0prev), [2048:2560)=Wih0 att part
__global__ void k_w0cat(const float* __restrict__ wih, const float* __restrict__ whh, f16* __restrict__ dst) {
  int j = blockIdx.y; int k = blockIdx.x * 256 + threadIdx.x;
  float v;
  if (k < 1024)      v = wih[(long)j * 1536 + k];
  else if (k < 2048) v = whh[(long)j * 1024 + (k - 1024)];
  else               v = wih[(long)j * 1536 + 1024 + (k - 2048)];
  dst[(long)j * 2560 + k] = (f16)v;
}
// w1cat cols: [0:1024)=Wih1 (z0), [1024:2048)=Whh1 (z1prev)
__global__ void k_w1cat(const float* __restrict__ wih, const float* __restrict__ whh, f16* __restrict__ dst) {
  int j = blockIdx.y; int k = blockIdx.x * 256 + threadIdx.x;
  float v = (k < 1024) ? wih[(long)j * 1024 + k] : whh[(long)j * 1024 + (k - 1024)];
  dst[(long)j * 2048 + k] = (f16)v;
}
__global__ void k_eys(const int* __restrict__ ys, const float* __restrict__ emb, f16* __restrict__ eys) {
  int sb = blockIdx.y; int k = blockIdx.x * 256 + threadIdx.x;
  int s = sb >> 5, b = sb & 31;
  int tok = (s == 0) ? SOS_ID : ys[b * 128 + (s - 1)];
  eys[(long)sb * 1024 + k] = (f16)emb[(long)tok * 1024 + k];
}
// preT[b][a][t] = tanh(hs[b][t][:].wenc[a][:] + benc[a])  (t-contiguous!)
__global__ void k_pre(const f16* __restrict__ hs, const f16* __restrict__ wenc,
                      const float* __restrict__ benc, f16* __restrict__ preT) {
  const int row0 = blockIdx.x * 32;
  for (int idx = threadIdx.x; idx < 32 * NA; idx += 256) {
    int r = row0 + idx / NA, a = idx % NA;
    const f16x8* hp = (const f16x8*)(hs + (long)r * NE);
    const f16x8* wp = (const f16x8*)(wenc + (long)a * NE);
    float acc = 0.f;
#pragma unroll 4
    for (int k = 0; k < 64; ++k) acc = dot8(hp[k], wp[k], acc);
    int b = r >> 9, t = r & 511;
    preT[((long)b * NA + a) * 512 + t] = (f16)tanhf_fast(acc + benc[a]);
  }
}
__global__ void k_bias(const float* a0, const float* b0, const float* a1, const float* b1,
                       float* s0, float* s1) {
  int i = blockIdx.x * 256 + threadIdx.x;
  if (i < 4096) { s0[i] = a0[i] + b0[i]; s1[i] = a1[i] + b1[i]; }
}
__global__ void k_zero(f16* dec, f16* z0, f16* z1, float* scal, unsigned* bar) {
  int i = blockIdx.x * 256 + threadIdx.x;  // grid 128 -> 32768
  if (i < NB * NA) dec[i] = (f16)0.f;
  if (i < NB * ND) { z0[i] = (f16)0.f; z1[i] = (f16)0.f; }
  if (i < 512) bar[i] = 0u;
  if (i < 8) scal[i] = 0.f;
}

// ------------------------------ persistent loop ----------------------------
struct LoopP {
  const f16 *preT, *hs, *eys, *w0, *w1, *wdec;
  const float *bs0, *bs1;
  const int* hlens;
  f16 *dec, *att, *z0h, *z1h, *zout;
  unsigned* bar;
};

__global__ void __launch_bounds__(256, 2) k_loop(LoopP p) {
  __shared__ __align__(16) f16 xs[32 * 516];   // 33024 B staging / att eL
  __shared__ float gacc[32 * 32];              // gate partial exchange
  __shared__ float cbuf[32 * 8];               // persistent c-state slice
  __shared__ float misc[1088];                 // decF[320] | wL[512] | red[256]

  const int bid = blockIdx.x, tid = threadIdx.x;
  const int bb = tid & 31, jsub = tid >> 5;
  cbuf[tid] = 0.f;   // 256 == 32*8
  __syncthreads();
  unsigned bidx = 0;

  // stage one 32x512 f16 tile into xs (stride 516)
  auto stage = [&](const f16* src, long rs, bool atomic) {
    for (int idx = tid; idx < 4096; idx += 256) {
      int r = idx >> 7, kk = idx & 127;
      const void* sp = (const void*)(src + (long)r * rs + kk * 4);
      unsigned long long v = atomic ? aload64(sp) : *(const unsigned long long*)sp;
      *(unsigned long long*)(xs + r * 516 + kk * 4) = v;
    }
  };

  if (bid < 128) {
    // ================= role g0: rows {g*1024 + h0 + hh} ====================
    const int h0 = bid * 8;
    const f16* wrow[4];
#pragma unroll
    for (int r = 0; r < 4; ++r) {
      int rr = jsub * 4 + r;
      wrow[r] = p.w0 + (long)((rr >> 3) * 1024 + h0 + (rr & 7)) * 2560;
    }
    const int decduty = (bid < 20);
    const int a0 = bid * 16;

    for (int s = 0; s < NL; ++s) {
      float acc0 = 0.f, acc1 = 0.f, acc2 = 0.f, acc3 = 0.f;
      // ---- Phase A: ey (K 0:1024) + z0prev (K 1024:2048) ----
      for (int kt = 0; kt < 4; ++kt) {
        if (kt < 2) stage(p.eys + (long)s * (NB * ND) + kt * 512, ND, false);
        else        stage(p.z0h + (kt - 2) * 512, ND, true);
        __syncthreads();
        const f16x4* xr = (const f16x4*)(xs + bb * 516);
        const f16x4* w0r = (const f16x4*)(wrow[0] + kt * 512);
        const f16x4* w1r = (const f16x4*)(wrow[1] + kt * 512);
        const f16x4* w2r = (const f16x4*)(wrow[2] + kt * 512);
        const f16x4* w3r = (const f16x4*)(wrow[3] + kt * 512);
#pragma unroll 8
        for (int kk = 0; kk < 128; ++kk) {
          f16x4 xv = xr[kk];
          acc0 = dot4(xv, w0r[kk], acc0);
          acc1 = dot4(xv, w1r[kk], acc1);
          acc2 = dot4(xv, w2r[kk], acc2);
          acc3 = dot4(xv, w3r[kk], acc3);
        }
        __syncthreads();
      }
      gbar2(p.bar, bid, ++bidx);

      // ---- Phase B: att part (K 2048:2560), finalize z0/c0 ----
      stage(p.att, NE, true);
      __syncthreads();
      {
        const f16x4* xr = (const f16x4*)(xs + bb * 516);
        const f16x4* w0r = (const f16x4*)(wrow[0] + 2048);
        const f16x4* w1r = (const f16x4*)(wrow[1] + 2048);
        const f16x4* w2r = (const f16x4*)(wrow[2] + 2048);
        const f16x4* w3r = (const f16x4*)(wrow[3] + 2048);
#pragma unroll 8
        for (int kk = 0; kk < 128; ++kk) {
          f16x4 xv = xr[kk];
          acc0 = dot4(xv, w0r[kk], acc0);
          acc1 = dot4(xv, w1r[kk], acc1);
          acc2 = dot4(xv, w2r[kk], acc2);
          acc3 = dot4(xv, w3r[kk], acc3);
        }
      }
      gacc[bb * 32 + jsub * 4 + 0] = acc0;
      gacc[bb * 32 + jsub * 4 + 1] = acc1;
      gacc[bb * 32 + jsub * 4 + 2] = acc2;
      gacc[bb * 32 + jsub * 4 + 3] = acc3;
      __syncthreads();
      if (tid < 128) {
        int b = tid & 31, hp = tid >> 5;
        float z[2];
#pragma unroll
        for (int u = 0; u < 2; ++u) {
          int hh = hp * 2 + u;
          float gi = gacc[b * 32 + hh]      + p.bs0[h0 + hh];
          float gf = gacc[b * 32 + 8 + hh]  + p.bs0[1024 + h0 + hh];
          float gv = gacc[b * 32 + 16 + hh] + p.bs0[2048 + h0 + hh];
          float go = gacc[b * 32 + 24 + hh] + p.bs0[3072 + h0 + hh];
          float cn = sigf(gf) * cbuf[b * 8 + hh] + sigf(gi) * tanhf_fast(gv);
          cbuf[b * 8 + hh] = cn;
          z[u] = sigf(go) * tanhf_fast(cn);
        }
        astore32((unsigned*)p.z0h + (b * ND + h0) / 2 + hp, pack2(z[0], z[1]));
      }
      gbar2(p.bar, bid, ++bidx);

      // ---- Phase C: dec(s+1) duty for blocks 0..19 ----
      if (decduty) {
        float d0 = 0.f, d1 = 0.f;
        const f16* wr0 = p.wdec + (long)(a0 + jsub * 2) * ND;
        const f16* wr1 = wr0 + ND;
        for (int kt = 0; kt < 2; ++kt) {
          stage(p.z0h + kt * 512, ND, true);
          __syncthreads();
          const f16x4* xr = (const f16x4*)(xs + bb * 516);
          const f16x4* w0r = (const f16x4*)(wr0 + kt * 512);
          const f16x4* w1r = (const f16x4*)(wr1 + kt * 512);
#pragma unroll 8
          for (int kk = 0; kk < 128; ++kk) {
            f16x4 xv = xr[kk];
            d0 = dot4(xv, w0r[kk], d0);
            d1 = dot4(xv, w1r[kk], d1);
          }
          __syncthreads();
        }
        astore32((unsigned*)p.dec + (bb * NA + a0) / 2 + jsub,
                 pack2(tanhf_fast(d0), tanhf_fast(d1)));
      }
      gbar2(p.bar, bid, ++bidx);
    }
  } else if (bid < 256) {
    // ================= role g1 =============================================
    const int h0 = (bid - 128) * 8;
    const f16* wrow[4];
#pragma unroll
    for (int r = 0; r < 4; ++r) {
      int rr = jsub * 4 + r;
      wrow[r] = p.w1 + (long)((rr >> 3) * 1024 + h0 + (rr & 7)) * 2048;
    }
    for (int s = 0; s < NL; ++s) {
      float acc0 = 0.f, acc1 = 0.f, acc2 = 0.f, acc3 = 0.f;
      // ---- Phase A: z1prev part (K 1024:2048) ----
      for (int kt = 0; kt < 2; ++kt) {
        stage(p.z1h + kt * 512, ND, true);
        __syncthreads();
        const f16x4* xr = (const f16x4*)(xs + bb * 516);
        const f16x4* w0r = (const f16x4*)(wrow[0] + 1024 + kt * 512);
        const f16x4* w1r = (const f16x4*)(wrow[1] + 1024 + kt * 512);
        const f16x4* w2r = (const f16x4*)(wrow[2] + 1024 + kt * 512);
        const f16x4* w3r = (const f16x4*)(wrow[3] + 1024 + kt * 512);
#pragma unroll 8
        for (int kk = 0; kk < 128; ++kk) {
          f16x4 xv = xr[kk];
          acc0 = dot4(xv, w0r[kk], acc0);
          acc1 = dot4(xv, w1r[kk], acc1);
          acc2 = dot4(xv, w2r[kk], acc2);
          acc3 = dot4(xv, w3r[kk], acc3);
        }
        __syncthreads();
      }
      gbar2(p.bar, bid, ++bidx);
      // ---- Phase B: idle ----
      gbar2(p.bar, bid, ++bidx);
      // ---- Phase C: z0 part (K 0:1024), finalize z1/c1 ----
      for (int kt = 0; kt < 2; ++kt) {
        stage(p.z0h + kt * 512, ND, true);
        __syncthreads();
        const f16x4* xr = (const f16x4*)(xs + bb * 516);
        const f16x4* w0r = (const f16x4*)(wrow[0] + kt * 512);
        const f16x4* w1r = (const f16x4*)(wrow[1] + kt * 512);
        const f16x4* w2r = (const f16x4*)(wrow[2] + kt * 512);
        const f16x4* w3r = (const f16x4*)(wrow[3] + kt * 512);
#pragma unroll 8
        for (int kk = 0; kk < 128; ++kk) {
          f16x4 xv = xr[kk];
          acc0 = dot4(xv, w0r[kk], acc0);
          acc1 = dot4(xv, w1r[kk], acc1);
          acc2 = dot4(xv, w2r[kk], acc2);
          acc3 = dot4(xv, w3r[kk], acc3);
        }
        __syncthreads();
      }
      gacc[bb * 32 + jsub * 4 + 0] = acc0;
      gacc[bb * 32 + jsub * 4 + 1] = acc1;
      gacc[bb * 32 + jsub * 4 + 2] = acc2;
      gacc[bb * 32 + jsub * 4 + 3] = acc3;
      __syncthreads();
      if (tid < 128) {
        int b = tid & 31, hp = tid >> 5;
        float z[2];
#pragma unroll
        for (int u = 0; u < 2; ++u) {
          int hh = hp * 2 + u;
          float gi = gacc[b * 32 + hh]      + p.bs1[h0 + hh];
          float gf = gacc[b * 32 + 8 + hh]  + p.bs1[1024 + h0 + hh];
          float gv = gacc[b * 32 + 16 + hh] + p.bs1[2048 + h0 + hh];
          float go = gacc[b * 32 + 24 + hh] + p.bs1[3072 + h0 + hh];
          float cn = sigf(gf) * cbuf[b * 8 + hh] + sigf(gi) * tanhf_fast(gv);
          cbuf[b * 8 + hh] = cn;
          z[u] = sigf(go) * tanhf_fast(cn);
        }
        unsigned pk = pack2(z[0], z[1]);
        astore32((unsigned*)p.z1h + (b * ND + h0) / 2 + hp, pk);
        *((unsigned*)p.zout + ((long)(s * 32 + b) * ND + h0) / 2 + hp) = pk;
      }
      gbar2(p.bar, bid, ++bidx);
    }
  } else {
    // ================= role attention (one block per batch b) ==============
    const int b = bid - 256;
    const int hlen = p.hlens[b];
    float* decF = misc;          // [320]
    float* wL   = misc + 320;    // [512]
    float* red  = misc + 832;    // [256]
    float* eL   = (float*)xs;    // [512]
    const unsigned* pa  = (const unsigned*)p.preT + (long)b * NA * 256 + tid;
    const unsigned* hp2 = (const unsigned*)p.hs  + (long)b * NTT * 256 + tid;

    for (int s = 0; s < NL; ++s) {
      // ---- Phase A: e, softmax, att_c ----
      if (tid < 80) {
        PU64 v; v.u = aload64((const unsigned long long*)p.dec + b * 80 + tid);
#pragma unroll
        for (int i = 0; i < 4; ++i) decF[tid * 4 + i] = (float)v.h[i];
      }
      __syncthreads();
      float e0 = 0.f, e1 = 0.f;
      for (int a = 0; a < NA; ++a) {
        PU32 pv; pv.u = pa[(long)a * 256];
        float d = decF[a];
        e0 += (float)pv.h[0] * d;
        e1 += (float)pv.h[1] * d;
      }
      e0 *= 2.0f; e1 *= 2.0f;  // SCALING
      int t0 = 2 * tid, t1 = 2 * tid + 1;
      float m0 = (t0 < hlen) ? e0 : -3e38f;
      float m1 = (t1 < hlen) ? e1 : -3e38f;
      red[tid] = fmaxf(m0, m1);
      __syncthreads();
      for (int st = 128; st > 0; st >>= 1) {
        if (tid < st) red[tid] = fmaxf(red[tid], red[tid + st]);
        __syncthreads();
      }
      const float M = red[0];
      __syncthreads();
      float w0 = (t0 < hlen) ? __expf(e0 - M) : 0.f;
      float w1 = (t1 < hlen) ? __expf(e1 - M) : 0.f;
      wL[t0] = w0; wL[t1] = w1;
      red[tid] = w0 + w1;
      __syncthreads();
      for (int st = 128; st > 0; st >>= 1) {
        if (tid < st) red[tid] += red[tid + st];
        __syncthreads();
      }
      const float inv = 1.0f / red[0];
      __syncthreads();
      float a0 = 0.f, a1 = 0.f;
      for (int t = 0; t < hlen; ++t) {
        PU32 hv; hv.u = hp2[(long)t * 256];
        float w = wL[t];
        a0 += w * (float)hv.h[0];
        a1 += w * (float)hv.h[1];
      }
      astore32((unsigned*)p.att + b * 256 + tid, pack2(a0 * inv, a1 * inv));
      gbar2(p.bar, bid, ++bidx);
      gbar2(p.bar, bid, ++bidx);
      gbar2(p.bar, bid, ++bidx);
    }
  }
}

// ------------------------- logits GEMM + fused CE stats --------------------
__global__ void __launch_bounds__(256) k_lgemm(const f16* __restrict__ z, const f16* __restrict__ wout,
                                               const float* __restrict__ bout, float4* __restrict__ part) {
  const int mb = blockIdx.x, nb = blockIdx.y;
  const int wid = threadIdx.x >> 6, lane = threadIdx.x & 63;
  const int lr = lane & 15, lq = lane >> 4;
  const int m0 = mb * 32;
  const int n0 = nb * 512 + wid * 128;
  const f16* arow0 = z + (long)(m0 + lr) * 1024 + lq * 8;
  const f16* arow1 = arow0 + (long)16 * 1024;
  const f16* bp[8];
  int cols[8];
#pragma unroll
  for (int nt = 0; nt < 8; ++nt) {
    int n = n0 + nt * 16 + lr;
    cols[nt] = n;
    int nc = (n < NO) ? n : (NO - 1);
    bp[nt] = wout + (long)nc * 1024 + lq * 8;
  }
  f32x4 acc[16];
#pragma unroll
  for (int i = 0; i < 16; ++i) acc[i] = (f32x4){0.f, 0.f, 0.f, 0.f};
  for (int kk = 0; kk < 1024; kk += 32) {
    f16x8 a0v = *(const f16x8*)(arow0 + kk);
    f16x8 a1v = *(const f16x8*)(arow1 + kk);
#pragma unroll
    for (int nt = 0; nt < 8; ++nt) {
      f16x8 bv = *(const f16x8*)(bp[nt] + kk);
      acc[nt]     = __builtin_amdgcn_mfma_f32_16x16x32_f16(a0v, bv, acc[nt], 0, 0, 0);
      acc[8 + nt] = __builtin_amdgcn_mfma_f32_16x16x32_f16(a1v, bv, acc[8 + nt], 0, 0, 0);
    }
  }
  float bias[8];
#pragma unroll
  for (int nt = 0; nt < 8; ++nt) bias[nt] = (cols[nt] < NO) ? bout[cols[nt]] : 0.f;
  const int chunk = nb * 4 + wid;
#pragma unroll
  for (int mt = 0; mt < 2; ++mt) {
#pragma unroll
    for (int reg = 0; reg < 4; ++reg) {
      float vals[8];
      float mx = -1e30f, av = -1e30f; int ai = 0;
#pragma unroll
      for (int nt = 0; nt < 8; ++nt) {
        float v = (cols[nt] < NO) ? (acc[mt * 8 + nt][reg] + bias[nt]) : -1e30f;
        vals[nt] = v;
        mx = fmaxf(mx, v);
        if (v > av) { av = v; ai = cols[nt]; }
      }
      float sum = 0.f;
#pragma unroll
      for (int nt = 0; nt < 8; ++nt) sum += (vals[nt] > -9e29f) ? __expf(vals[nt] - mx) : 0.f;
#pragma unroll
      for (int off = 1; off < 16; off <<= 1) {
        float mo = __shfl_xor(mx, off);
        float so = __shfl_xor(sum, off);
        float avo = __shfl_xor(av, off);
        int aio = __shfl_xor(ai, off);
        float nm = fmaxf(mx, mo);
        float e1 = (mx > -9e29f) ? __expf(mx - nm) : 0.f;
        float e2 = (mo > -9e29f) ? __expf(mo - nm) : 0.f;
        sum = sum * e1 + so * e2;
        mx = nm;
        if (avo > av || (avo == av && aio < ai)) { av = avo; ai = aio; }
      }
      if (lr == 0) {
        int rowg = m0 + mt * 16 + lq * 4 + reg;
        float4 q; q.x = mx; q.y = sum; q.z = av; q.w = __int_as_float(ai);
        part[(long)rowg * 80 + chunk] = q;
      }
    }
  }
}

__global__ void k_tl(const f16* __restrict__ z, const f16* __restrict__ wout,
                     const float* __restrict__ bout, const int* __restrict__ ys, float* __restrict__ tl) {
  const int tok = blockIdx.x * 4 + (threadIdx.x >> 6);
  const int lane = threadIdx.x & 63;
  if (tok >= NTOK) return;
  const int s = tok >> 5, b = tok & 31;
  const int tgt = (s < 128) ? ys[b * 128 + s] : SOS_ID;
  const f16x8* zp = (const f16x8*)(z + (long)tok * 1024);
  const f16x8* wp = (const f16x8*)(wout + (long)tgt * 1024);
  float acc = 0.f;
  acc = dot8(zp[lane], wp[lane], acc);
  acc = dot8(zp[64 + lane], wp[64 + lane], acc);
#pragma unroll
  for (int off = 32; off > 0; off >>= 1) acc += __shfl_xor(acc, off);
  if (lane == 0) tl[tok] = acc + bout[tgt];
}

__global__ void k_ce(const float4* __restrict__ part, const float* __restrict__ tl,
                     const int* __restrict__ ys, float* scal) {
  const int m = blockIdx.x * 256 + threadIdx.x;
  float nll = 0.f, okf = 0.f;
  if (m < NTOK) {
    float M = -1e30f, S = 0.f, av = -1e30f; int ai = 0;
    for (int c = 0; c < 80; ++c) {
      float4 q = part[(long)m * 80 + c];
      float qm = q.x, qs = q.y, qa = q.z; int qi = __float_as_int(q.w);
      float nm = fmaxf(M, qm);
      float e1 = (M > -9e29f) ? __expf(M - nm) : 0.f;
      float e2 = (qm > -9e29f) ? __expf(qm - nm) : 0.f;
      S = S * e1 + qs * e2; M = nm;
      if (qa > av || (qa == av && qi < ai)) { av = qa; ai = qi; }
    }
    float lse = M + __logf(S);
    int s = m >> 5, b = m & 31;
    int tgt = (s < 128) ? ys[b * 128 + s] : SOS_ID;
    nll = lse - tl[m];
    okf = (ai == tgt) ? 1.f : 0.f;
  }
  __shared__ float r1[256], r2[256];
  r1[threadIdx.x] = nll; r2[threadIdx.x] = okf; __syncthreads();
  for (int st = 128; st > 0; st >>= 1) {
    if (threadIdx.x < st) { r1[threadIdx.x] += r1[threadIdx.x + st]; r2[threadIdx.x] += r2[threadIdx.x + st]; }
    __syncthreads();
  }
  if (threadIdx.x == 0) { atomicAdd(&scal[0], r1[0]); atomicAdd(&scal[1], r2[0]); }
}

__global__ void k_final(const float* scal, float* out) {
  if (threadIdx.x == 0) {
    float loss = scal[0] * (128.f / 4128.f);
    out[0] = loss;
    out[1] = scal[1] * (1.f / 4128.f);
    out[2] = expf(loss / 32.f);
  }
}

// --------------------------------- launch ----------------------------------
extern "C" void kernel_launch(void* const* d_in, const int* in_sizes, int n_in,
                              void* d_out, int out_size, void* d_ws, size_t ws_size,
                              hipStream_t stream) {
  const float* hs_pad = (const float*)d_in[0];
  const int* hlens    = (const int*)d_in[1];
  const int* ys_pad   = (const int*)d_in[2];
  const float* embed  = (const float*)d_in[3];
  const float* Wenc   = (const float*)d_in[4];
  const float* benc   = (const float*)d_in[5];
  const float* Wdec   = (const float*)d_in[6];
  const float* Wih0   = (const float*)d_in[7];
  const float* Whh0   = (const float*)d_in[8];
  const float* bih0   = (const float*)d_in[9];
  const float* bhh0   = (const float*)d_in[10];
  const float* Wih1   = (const float*)d_in[11];
  const float* Whh1   = (const float*)d_in[12];
  const float* bih1   = (const float*)d_in[13];
  const float* bhh1   = (const float*)d_in[14];
  const float* Wout   = (const float*)d_in[15];
  const float* bout   = (const float*)d_in[16];
  float* out = (float*)d_out;
  (void)in_sizes; (void)n_in; (void)out_size; (void)ws_size;

  char* ws = (char*)d_ws;
  size_t off = 0;
  auto alloc = [&](size_t bytes) -> char* {
    char* pp = ws + off;
    off = (off + bytes + 255) & ~(size_t)255;
    return pp;
  };
  f16* hs16    = (f16*)alloc((size_t)NB * NTT * NE * 2);
  f16* preT    = (f16*)alloc((size_t)NB * NA * NTT * 2);
  f16* eys16   = (f16*)alloc((size_t)NL * NB * ND * 2);
  f16* w0cat   = (f16*)alloc((size_t)4096 * 2560 * 2);
  f16* w1cat   = (f16*)alloc((size_t)4096 * 2048 * 2);
  f16* wdec16  = (f16*)alloc((size_t)NA * ND * 2);
  f16* wenc16  = (f16*)alloc((size_t)NA * NE * 2);
  f16* wout16  = (f16*)alloc((size_t)NO * ND * 2);
  f16* zout    = (f16*)alloc((size_t)NTOK * ND * 2);
  f16* z0h     = (f16*)alloc((size_t)NB * ND * 2);
  f16* z1h     = (f16*)alloc((size_t)NB * ND * 2);
  f16* dec16   = (f16*)alloc((size_t)NB * NA * 2);
  f16* att16   = (f16*)alloc((size_t)NB * NE * 2);
  float* bs0   = (float*)alloc(4096 * 4);
  float* bs1   = (float*)alloc(4096 * 4);
  float* tl    = (float*)alloc((size_t)NTOK * 4);
  float4* part = (float4*)alloc((size_t)NTOK * 80 * 16);
  float* scal  = (float*)alloc(256);
  unsigned* bar = (unsigned*)alloc(2048);

  k_cvt<<<dim3(2048), dim3(256), 0, stream>>>(hs_pad, hs16, (long)NB * NTT * NE);
  k_cvt<<<dim3(256), dim3(256), 0, stream>>>(Wdec, wdec16, (long)NA * ND);
  k_cvt<<<dim3(128), dim3(256), 0, stream>>>(Wenc, wenc16, (long)NA * NE);
  k_cvt<<<dim3(2048), dim3(256), 0, stream>>>(Wout, wout16, (long)NO * ND);
  k_w0cat<<<dim3(10, 4096), dim3(256), 0, stream>>>(Wih0, Whh0, w0cat);
  k_w1cat<<<dim3(8, 4096), dim3(256), 0, stream>>>(Wih1, Whh1, w1cat);
  k_eys<<<dim3(4, NL * NB), dim3(256), 0, stream>>>(ys_pad, embed, eys16);
  k_pre<<<dim3(512), dim3(256), 0, stream>>>(hs16, wenc16, benc, preT);
  k_bias<<<dim3(16), dim3(256), 0, stream>>>(bih0, bhh0, bih1, bhh1, bs0, bs1);
  k_zero<<<dim3(128), dim3(256), 0, stream>>>(dec16, z0h, z1h, scal, bar);

  LoopP lp;
  lp.preT = preT; lp.hs = hs16; lp.eys = eys16; lp.w0 = w0cat; lp.w1 = w1cat; lp.wdec = wdec16;
  lp.bs0 = bs0; lp.bs1 = bs1; lp.hlens = hlens;
  lp.dec = dec16; lp.att = att16; lp.z0h = z0h; lp.z1h = z1h; lp.zout = zout; lp.bar = bar;
  k_loop<<<dim3(GRID_LOOP), dim3(256), 0, stream>>>(lp);

  k_tl<<<dim3(NTOK / 4), dim3(256), 0, stream>>>(zout, wout16, bout, ys_pad, tl);
  k_lgemm<<<dim3(129, 20), dim3(256), 0, stream>>>(zout, wout16, bout, part);
  k_ce<<<dim3(17), dim3(256), 0, stream>>>(part, tl, ys_pad, scal);
  k_final<<<dim3(1), dim3(64), 0, stream>>>(scal, out);
}

// Round 4
// 12993.922 us; speedup vs baseline: 14.8754x; 1.1155x over previous
//
#include <hip/hip_runtime.h>
#include <hip/hip_fp16.h>
#include <math.h>

// ---------------------------------------------------------------------------
// Decoder (ESPnet AttDot + 2x LSTMCell + CE) on gfx950.
// R3 -> R4: recurrent GEMMs moved to MFMA 16x16x32 f16.
//  R3 flaw: dot4 GEMM had 32 lanes loading IDENTICAL weight addresses ->
//  32x L1 traffic amplification (5.2 MB/block/step for 160 KB unique),
//  VALU stalled at 10.5%. MFMA B-fragments are per-lane unique (16B loads),
//  A-fragments from LDS (stride 520 -> even bank coverage for b128 reads).
//  Att-role reductions now wave-shuffle based. Dataflow/barriers unchanged.
// ---------------------------------------------------------------------------

typedef _Float16 f16;
typedef _Float16 f16x2 __attribute__((ext_vector_type(2)));
typedef _Float16 f16x4 __attribute__((ext_vector_type(4)));
typedef _Float16 f16x8 __attribute__((ext_vector_type(8)));
typedef float f32x4 __attribute__((ext_vector_type(4)));

#define SOS_ID 9999
#define NB 32
#define NTT 512
#define NE 512
#define ND 1024
#define NA 320
#define NO 10000
#define NL 129
#define NTOK (NL*NB)
#define GRID_LOOP 288   // 128 g0 + 128 g1 + 32 att

union PU32 { unsigned u; f16x2 h; };
union PU64 { unsigned long long u; f16x4 h; unsigned w[2]; };

__device__ __forceinline__ float fdot2f(f16x2 a, f16x2 b, float c) {
#if __has_builtin(__builtin_amdgcn_fdot2)
  return __builtin_amdgcn_fdot2(a, b, c, false);
#else
  return c + (float)a[0]*(float)b[0] + (float)a[1]*(float)b[1];
#endif
}
__device__ __forceinline__ float dot8(f16x8 a, f16x8 b, float acc) {
  acc = fdot2f(__builtin_shufflevector(a, a, 0, 1), __builtin_shufflevector(b, b, 0, 1), acc);
  acc = fdot2f(__builtin_shufflevector(a, a, 2, 3), __builtin_shufflevector(b, b, 2, 3), acc);
  acc = fdot2f(__builtin_shufflevector(a, a, 4, 5), __builtin_shufflevector(b, b, 4, 5), acc);
  acc = fdot2f(__builtin_shufflevector(a, a, 6, 7), __builtin_shufflevector(b, b, 6, 7), acc);
  return acc;
}
__device__ __forceinline__ float sigf(float x) { return 1.0f / (1.0f + __expf(-x)); }
__device__ __forceinline__ float tanhf_fast(float x) { return 1.0f - 2.0f / (1.0f + __expf(2.0f * x)); }

__device__ __forceinline__ unsigned long long aload64(const void* p) {
  return __hip_atomic_load((const unsigned long long*)p, __ATOMIC_RELAXED, __HIP_MEMORY_SCOPE_AGENT);
}
__device__ __forceinline__ void astore32(void* p, unsigned v) {
  __hip_atomic_store((unsigned*)p, v, __ATOMIC_RELAXED, __HIP_MEMORY_SCOPE_AGENT);
}
__device__ __forceinline__ unsigned pack2(float a, float b) {
  PU32 u; u.h[0] = (f16)a; u.h[1] = (f16)b; return u.u;
}

// Two-level monotonic barrier (8 sub-counters + root + flag). No acquire
// fences anywhere: mutable data moves via agent-scope atomics only.
__device__ __forceinline__ void gbar2(unsigned* bar, int bid, unsigned idx) {
  __syncthreads();
  if (threadIdx.x == 0) {
    unsigned old = __hip_atomic_fetch_add(&bar[(bid & 7) * 32], 1u, __ATOMIC_RELEASE, __HIP_MEMORY_SCOPE_AGENT);
    if (old + 1u == idx * (GRID_LOOP / 8)) {
      unsigned r = __hip_atomic_fetch_add(&bar[256], 1u, __ATOMIC_RELEASE, __HIP_MEMORY_SCOPE_AGENT);
      if (r + 1u == idx * 8u)
        __hip_atomic_store(&bar[288], idx, __ATOMIC_RELEASE, __HIP_MEMORY_SCOPE_AGENT);
    }
    while (__hip_atomic_load(&bar[288], __ATOMIC_RELAXED, __HIP_MEMORY_SCOPE_AGENT) < idx)
      __builtin_amdgcn_s_sleep(16);
  }
  __syncthreads();
  asm volatile("" ::: "memory");
}

// ------------------------------ prep kernels -------------------------------
__global__ void k_cvt(const float* __restrict__ s, f16* __restrict__ d, long n) {
  long i = (long)blockIdx.x * 256 + threadIdx.x;
  long st = (long)gridDim.x * 256;
  for (; i < n; i += st) d[i] = (f16)s[i];
}
// w0cat cols: [0:1024)=Wih0 ey part, [1024:2048)=Whh0 (z0prev), [2048:2560)=Wih0 att part
__global__ void k_w0cat(const float* __restrict__ wih, const float* __restrict__ whh, f16* __restrict__ dst) {
  int j = blockIdx.y; int k = blockIdx.x * 256 + threadIdx.x;
  float v;
  if (k < 1024)      v = wih[(long)j * 1536 + k];
  else if (k < 2048) v = whh[(long)j * 1024 + (k - 1024)];
  else               v = wih[(long)j * 1536 + 1024 + (k - 2048)];
  dst[(long)j * 2560 + k] = (f16)v;
}
// w1cat cols: [0:1024)=Wih1 (z0), [1024:2048)=Whh1 (z1prev)
__global__ void k_w1cat(const float* __restrict__ wih, const float* __restrict__ whh, f16* __restrict__ dst) {
  int j = blockIdx.y; int k = blockIdx.x * 256 + threadIdx.x;
  float v = (k < 1024) ? wih[(long)j * 1024 + k] : whh[(long)j * 1024 + (k - 1024)];
  dst[(long)j * 2048 + k] = (f16)v;
}
__global__ void k_eys(const int* __restrict__ ys, const float* __restrict__ emb, f16* __restrict__ eys) {
  int sb = blockIdx.y; int k = blockIdx.x * 256 + threadIdx.x;
  int s = sb >> 5, b = sb & 31;
  int tok = (s == 0) ? SOS_ID : ys[b * 128 + (s - 1)];
  eys[(long)sb * 1024 + k] = (f16)emb[(long)tok * 1024 + k];
}
// preT[b][a][t] = tanh(hs[b][t][:].wenc[a][:] + benc[a])  (t-contiguous)
__global__ void k_pre(const f16* __restrict__ hs, const f16* __restrict__ wenc,
                      const float* __restrict__ benc, f16* __restrict__ preT) {
  const int row0 = blockIdx.x * 32;
  for (int idx = threadIdx.x; idx < 32 * NA; idx += 256) {
    int r = row0 + idx / NA, a = idx % NA;
    const f16x8* hp = (const f16x8*)(hs + (long)r * NE);
    const f16x8* wp = (const f16x8*)(wenc + (long)a * NE);
    float acc = 0.f;
#pragma unroll 4
    for (int k = 0; k < 64; ++k) acc = dot8(hp[k], wp[k], acc);
    int b = r >> 9, t = r & 511;
    preT[((long)b * NA + a) * 512 + t] = (f16)tanhf_fast(acc + benc[a]);
  }
}
__global__ void k_bias(const float* a0, const float* b0, const float* a1, const float* b1,
                       float* s0, float* s1) {
  int i = blockIdx.x * 256 + threadIdx.x;
  if (i < 4096) { s0[i] = a0[i] + b0[i]; s1[i] = a1[i] + b1[i]; }
}
__global__ void k_zero(f16* dec, f16* z0, f16* z1, float* scal, unsigned* bar) {
  int i = blockIdx.x * 256 + threadIdx.x;
  if (i < NB * NA) dec[i] = (f16)0.f;
  if (i < NB * ND) { z0[i] = (f16)0.f; z1[i] = (f16)0.f; }
  if (i < 512) bar[i] = 0u;
  if (i < 8) scal[i] = 0.f;
}

// ------------------------------ persistent loop ----------------------------
struct LoopP {
  const f16 *preT, *hs, *eys, *w0, *w1, *wdec;
  const float *bs0, *bs1;
  const int* hlens;
  f16 *dec, *att, *z0h, *z1h, *zout;
  unsigned* bar;
};

__global__ void __launch_bounds__(256, 2) k_loop(LoopP p) {
  __shared__ __align__(16) f16 xs[32 * 520];   // 33280 B activation tile
  __shared__ float gacc[32 * 33];              // gate partial exchange (pad 33)
  __shared__ float cbuf[256];                  // c-state slice / att reduce

  const int bid = blockIdx.x, tid = threadIdx.x;
  const int wid = tid >> 6, lane = tid & 63, lr = lane & 15, lq = lane >> 4;
  cbuf[tid] = 0.f;
  __syncthreads();
  unsigned bidx = 0;

  // stage one 32x512 f16 tile into xs (row stride 520)
  auto stage = [&](const f16* src, long rs, bool atomic) {
    for (int idx = tid; idx < 4096; idx += 256) {
      int r = idx >> 7, c = idx & 127;
      const void* sp = (const void*)(src + (long)r * rs + c * 4);
      unsigned long long v = atomic ? aload64(sp) : *(const unsigned long long*)sp;
      *(unsigned long long*)(xs + r * 520 + c * 4) = v;
    }
  };

  if (bid < 256) {
    // ================= roles g0 / g1: MFMA gate GEMMs ======================
    const bool is0 = (bid < 128);
    const int h0 = (is0 ? bid : bid - 128) * 8;
    const int mt = wid >> 1, nt = wid & 1;
    const int rrow = nt * 16 + lr;                   // 0..31 = gate*8 + hh
    const long wstride = is0 ? 2560 : 2048;
    const f16* wbase = (is0 ? p.w0 : p.w1) + (long)((rrow >> 3) * 1024 + h0 + (rrow & 7)) * wstride + lq * 8;
    const f16* aptr = xs + (mt * 16 + lr) * 520 + lq * 8;
    const float* bs = is0 ? p.bs0 : p.bs1;
    const bool decduty = is0 && bid < 20;
    const int a0 = bid * 16;
    const f16* wdrow = p.wdec + (long)(a0 + lr) * ND + lq * 8;

    for (int s = 0; s < NL; ++s) {
      f32x4 acc = (f32x4){0.f, 0.f, 0.f, 0.f};
      // ---- Phase A ----
      if (is0) {
        // ey (K 0:1024) + z0prev (K 1024:2048)
        for (int kt = 0; kt < 4; ++kt) {
          if (kt < 2) stage(p.eys + (long)s * (NB * ND) + kt * 512, ND, false);
          else        stage(p.z0h + (kt - 2) * 512, ND, true);
          __syncthreads();
          const f16* wk = wbase + kt * 512;
#pragma unroll
          for (int kk = 0; kk < 512; kk += 32)
            acc = __builtin_amdgcn_mfma_f32_16x16x32_f16(
                *(const f16x8*)(aptr + kk), *(const f16x8*)(wk + kk), acc, 0, 0, 0);
          __syncthreads();
        }
      } else {
        // z1prev part (K 1024:2048)
        for (int kt = 0; kt < 2; ++kt) {
          stage(p.z1h + kt * 512, ND, true);
          __syncthreads();
          const f16* wk = wbase + 1024 + kt * 512;
#pragma unroll
          for (int kk = 0; kk < 512; kk += 32)
            acc = __builtin_amdgcn_mfma_f32_16x16x32_f16(
                *(const f16x8*)(aptr + kk), *(const f16x8*)(wk + kk), acc, 0, 0, 0);
          __syncthreads();
        }
      }
      gbar2(p.bar, bid, ++bidx);

      // ---- Phase B: g0 att part + finalize z0/c0; g1 idle ----
      if (is0) {
        stage(p.att, NE, true);
        __syncthreads();
        const f16* wk = wbase + 2048;
#pragma unroll
        for (int kk = 0; kk < 512; kk += 32)
          acc = __builtin_amdgcn_mfma_f32_16x16x32_f16(
              *(const f16x8*)(aptr + kk), *(const f16x8*)(wk + kk), acc, 0, 0, 0);
#pragma unroll
        for (int reg = 0; reg < 4; ++reg)
          gacc[(mt * 16 + lq * 4 + reg) * 33 + rrow] = acc[reg];
        __syncthreads();
        if (tid < 128) {
          int b = tid & 31, hp = tid >> 5;
          float z[2];
#pragma unroll
          for (int u = 0; u < 2; ++u) {
            int hh = hp * 2 + u;
            float gi = gacc[b * 33 + hh]      + bs[h0 + hh];
            float gf = gacc[b * 33 + 8 + hh]  + bs[1024 + h0 + hh];
            float gv = gacc[b * 33 + 16 + hh] + bs[2048 + h0 + hh];
            float go = gacc[b * 33 + 24 + hh] + bs[3072 + h0 + hh];
            float cn = sigf(gf) * cbuf[b * 8 + hh] + sigf(gi) * tanhf_fast(gv);
            cbuf[b * 8 + hh] = cn;
            z[u] = sigf(go) * tanhf_fast(cn);
          }
          astore32((unsigned*)p.z0h + (b * ND + h0) / 2 + hp, pack2(z[0], z[1]));
        }
      }
      gbar2(p.bar, bid, ++bidx);

      // ---- Phase C ----
      if (!is0) {
        // g1: z0 part (K 0:1024) + finalize z1/c1
        for (int kt = 0; kt < 2; ++kt) {
          stage(p.z0h + kt * 512, ND, true);
          __syncthreads();
          const f16* wk = wbase + kt * 512;
#pragma unroll
          for (int kk = 0; kk < 512; kk += 32)
            acc = __builtin_amdgcn_mfma_f32_16x16x32_f16(
                *(const f16x8*)(aptr + kk), *(const f16x8*)(wk + kk), acc, 0, 0, 0);
          __syncthreads();
        }
#pragma unroll
        for (int reg = 0; reg < 4; ++reg)
          gacc[(mt * 16 + lq * 4 + reg) * 33 + rrow] = acc[reg];
        __syncthreads();
        if (tid < 128) {
          int b = tid & 31, hp = tid >> 5;
          float z[2];
#pragma unroll
          for (int u = 0; u < 2; ++u) {
            int hh = hp * 2 + u;
            float gi = gacc[b * 33 + hh]      + bs[h0 + hh];
            float gf = gacc[b * 33 + 8 + hh]  + bs[1024 + h0 + hh];
            float gv = gacc[b * 33 + 16 + hh] + bs[2048 + h0 + hh];
            float go = gacc[b * 33 + 24 + hh] + bs[3072 + h0 + hh];
            float cn = sigf(gf) * cbuf[b * 8 + hh] + sigf(gi) * tanhf_fast(gv);
            cbuf[b * 8 + hh] = cn;
            z[u] = sigf(go) * tanhf_fast(cn);
          }
          unsigned pk = pack2(z[0], z[1]);
          astore32((unsigned*)p.z1h + (b * ND + h0) / 2 + hp, pk);
          *((unsigned*)p.zout + ((long)(s * 32 + b) * ND + h0) / 2 + hp) = pk;
        }
      } else if (decduty) {
        // dec(s+1) = tanh(z0 @ Wdec^T), rows a0..a0+15, MFMA (waves 0,1)
        f32x4 dacc = (f32x4){0.f, 0.f, 0.f, 0.f};
        for (int kt = 0; kt < 2; ++kt) {
          stage(p.z0h + kt * 512, ND, true);
          __syncthreads();
          if (wid < 2) {
            const f16* ap2 = xs + (wid * 16 + lr) * 520 + lq * 8;
            const f16* wk = wdrow + kt * 512;
#pragma unroll
            for (int kk = 0; kk < 512; kk += 32)
              dacc = __builtin_amdgcn_mfma_f32_16x16x32_f16(
                  *(const f16x8*)(ap2 + kk), *(const f16x8*)(wk + kk), dacc, 0, 0, 0);
          }
          __syncthreads();
        }
        if (wid < 2) {
#pragma unroll
          for (int reg = 0; reg < 4; ++reg)
            gacc[(wid * 16 + lq * 4 + reg) * 33 + lr] = tanhf_fast(dacc[reg]);
        }
        __syncthreads();
        {
          int b = tid & 31, j = tid >> 5;  // j 0..7 covers 16 cols
          astore32((unsigned*)p.dec + (b * NA + a0) / 2 + j,
                   pack2(gacc[b * 33 + 2 * j], gacc[b * 33 + 2 * j + 1]));
        }
      }
      gbar2(p.bar, bid, ++bidx);
    }
  } else {
    // ================= role attention (one block per batch b) ==============
    const int b = bid - 256;
    const int hlen = p.hlens[b];
    float* decF = gacc;            // [320]
    float* wL   = (float*)xs;      // [512]
    float* red  = cbuf;            // [4] per reduce
    const unsigned* pa  = (const unsigned*)p.preT + (long)b * NA * 256 + tid;
    const unsigned* hp2 = (const unsigned*)p.hs  + (long)b * NTT * 256 + tid;

    for (int s = 0; s < NL; ++s) {
      // ---- Phase A: e, softmax, att_c ----
      if (tid < 80) {
        PU64 v; v.u = aload64((const unsigned long long*)p.dec + b * 80 + tid);
#pragma unroll
        for (int i = 0; i < 4; ++i) decF[tid * 4 + i] = (float)v.h[i];
      }
      __syncthreads();
      float e0 = 0.f, e1 = 0.f;
#pragma unroll 4
      for (int a = 0; a < NA; ++a) {
        PU32 pv; pv.u = pa[(long)a * 256];
        float d = decF[a];
        e0 += (float)pv.h[0] * d;
        e1 += (float)pv.h[1] * d;
      }
      e0 *= 2.0f; e1 *= 2.0f;  // SCALING
      int t0 = 2 * tid, t1 = 2 * tid + 1;
      float m = fmaxf((t0 < hlen) ? e0 : -3e38f, (t1 < hlen) ? e1 : -3e38f);
#pragma unroll
      for (int off = 1; off < 64; off <<= 1) m = fmaxf(m, __shfl_xor(m, off));
      if (lane == 0) red[wid] = m;
      __syncthreads();
      const float M = fmaxf(fmaxf(red[0], red[1]), fmaxf(red[2], red[3]));
      float w0 = (t0 < hlen) ? __expf(e0 - M) : 0.f;
      float w1 = (t1 < hlen) ? __expf(e1 - M) : 0.f;
      wL[t0] = w0; wL[t1] = w1;
      float sm = w0 + w1;
#pragma unroll
      for (int off = 1; off < 64; off <<= 1) sm += __shfl_xor(sm, off);
      __syncthreads();               // wL visible + red reusable
      if (lane == 0) red[wid] = sm;
      __syncthreads();
      const float inv = 1.0f / (red[0] + red[1] + red[2] + red[3]);
      float a0 = 0.f, a1 = 0.f;
#pragma unroll 4
      for (int t = 0; t < hlen; ++t) {
        PU32 hv; hv.u = hp2[(long)t * 256];
        float w = wL[t];
        a0 += w * (float)hv.h[0];
        a1 += w * (float)hv.h[1];
      }
      astore32((unsigned*)p.att + b * 256 + tid, pack2(a0 * inv, a1 * inv));
      gbar2(p.bar, bid, ++bidx);
      gbar2(p.bar, bid, ++bidx);
      gbar2(p.bar, bid, ++bidx);
    }
  }
}

// ------------------------- logits GEMM + fused CE stats --------------------
__global__ void __launch_bounds__(256) k_lgemm(const f16* __restrict__ z, const f16* __restrict__ wout,
                                               const float* __restrict__ bout, float4* __restrict__ part) {
  const int mb = blockIdx.x, nb = blockIdx.y;
  const int wid = threadIdx.x >> 6, lane = threadIdx.x & 63;
  const int lr = lane & 15, lq = lane >> 4;
  const int m0 = mb * 32;
  const int n0 = nb * 512 + wid * 128;
  const f16* arow0 = z + (long)(m0 + lr) * 1024 + lq * 8;
  const f16* arow1 = arow0 + (long)16 * 1024;
  const f16* bp[8];
  int cols[8];
#pragma unroll
  for (int nt = 0; nt < 8; ++nt) {
    int n = n0 + nt * 16 + lr;
    cols[nt] = n;
    int nc = (n < NO) ? n : (NO - 1);
    bp[nt] = wout + (long)nc * 1024 + lq * 8;
  }
  f32x4 acc[16];
#pragma unroll
  for (int i = 0; i < 16; ++i) acc[i] = (f32x4){0.f, 0.f, 0.f, 0.f};
  for (int kk = 0; kk < 1024; kk += 32) {
    f16x8 a0v = *(const f16x8*)(arow0 + kk);
    f16x8 a1v = *(const f16x8*)(arow1 + kk);
#pragma unroll
    for (int nt = 0; nt < 8; ++nt) {
      f16x8 bv = *(const f16x8*)(bp[nt] + kk);
      acc[nt]     = __builtin_amdgcn_mfma_f32_16x16x32_f16(a0v, bv, acc[nt], 0, 0, 0);
      acc[8 + nt] = __builtin_amdgcn_mfma_f32_16x16x32_f16(a1v, bv, acc[8 + nt], 0, 0, 0);
    }
  }
  float bias[8];
#pragma unroll
  for (int nt = 0; nt < 8; ++nt) bias[nt] = (cols[nt] < NO) ? bout[cols[nt]] : 0.f;
  const int chunk = nb * 4 + wid;
#pragma unroll
  for (int mt = 0; mt < 2; ++mt) {
#pragma unroll
    for (int reg = 0; reg < 4; ++reg) {
      float vals[8];
      float mx = -1e30f, av = -1e30f; int ai = 0;
#pragma unroll
      for (int nt = 0; nt < 8; ++nt) {
        float v = (cols[nt] < NO) ? (acc[mt * 8 + nt][reg] + bias[nt]) : -1e30f;
        vals[nt] = v;
        mx = fmaxf(mx, v);
        if (v > av) { av = v; ai = cols[nt]; }
      }
      float sum = 0.f;
#pragma unroll
      for (int nt = 0; nt < 8; ++nt) sum += (vals[nt] > -9e29f) ? __expf(vals[nt] - mx) : 0.f;
#pragma unroll
      for (int off = 1; off < 16; off <<= 1) {
        float mo = __shfl_xor(mx, off);
        float so = __shfl_xor(sum, off);
        float avo = __shfl_xor(av, off);
        int aio = __shfl_xor(ai, off);
        float nm = fmaxf(mx, mo);
        float e1 = (mx > -9e29f) ? __expf(mx - nm) : 0.f;
        float e2 = (mo > -9e29f) ? __expf(mo - nm) : 0.f;
        sum = sum * e1 + so * e2;
        mx = nm;
        if (avo > av || (avo == av && aio < ai)) { av = avo; ai = aio; }
      }
      if (lr == 0) {
        int rowg = m0 + mt * 16 + lq * 4 + reg;
        float4 q; q.x = mx; q.y = sum; q.z = av; q.w = __int_as_float(ai);
        part[(long)rowg * 80 + chunk] = q;
      }
    }
  }
}

__global__ void k_tl(const f16* __restrict__ z, const f16* __restrict__ wout,
                     const float* __restrict__ bout, const int* __restrict__ ys, float* __restrict__ tl) {
  const int tok = blockIdx.x * 4 + (threadIdx.x >> 6);
  const int lane = threadIdx.x & 63;
  if (tok >= NTOK) return;
  const int s = tok >> 5, b = tok & 31;
  const int tgt = (s < 128) ? ys[b * 128 + s] : SOS_ID;
  const f16x8* zp = (const f16x8*)(z + (long)tok * 1024);
  const f16x8* wp = (const f16x8*)(wout + (long)tgt * 1024);
  float acc = 0.f;
  acc = dot8(zp[lane], wp[lane], acc);
  acc = dot8(zp[64 + lane], wp[64 + lane], acc);
#pragma unroll
  for (int off = 32; off > 0; off >>= 1) acc += __shfl_xor(acc, off);
  if (lane == 0) tl[tok] = acc + bout[tgt];
}

__global__ void k_ce(const float4* __restrict__ part, const float* __restrict__ tl,
                     const int* __restrict__ ys, float* scal) {
  const int m = blockIdx.x * 256 + threadIdx.x;
  float nll = 0.f, okf = 0.f;
  if (m < NTOK) {
    float M = -1e30f, S = 0.f, av = -1e30f; int ai = 0;
    for (int c = 0; c < 80; ++c) {
      float4 q = part[(long)m * 80 + c];
      float qm = q.x, qs = q.y, qa = q.z; int qi = __float_as_int(q.w);
      float nm = fmaxf(M, qm);
      float e1 = (M > -9e29f) ? __expf(M - nm) : 0.f;
      float e2 = (qm > -9e29f) ? __expf(qm - nm) : 0.f;
      S = S * e1 + qs * e2; M = nm;
      if (qa > av || (qa == av && qi < ai)) { av = qa; ai = qi; }
    }
    float lse = M + __logf(S);
    int s = m >> 5, b = m & 31;
    int tgt = (s < 128) ? ys[b * 128 + s] : SOS_ID;
    nll = lse - tl[m];
    okf = (ai == tgt) ? 1.f : 0.f;
  }
  __shared__ float r1[256], r2[256];
  r1[threadIdx.x] = nll; r2[threadIdx.x] = okf; __syncthreads();
  for (int st = 128; st > 0; st >>= 1) {
    if (threadIdx.x < st) { r1[threadIdx.x] += r1[threadIdx.x + st]; r2[threadIdx.x] += r2[threadIdx.x + st]; }
    __syncthreads();
  }
  if (threadIdx.x == 0) { atomicAdd(&scal[0], r1[0]); atomicAdd(&scal[1], r2[0]); }
}

__global__ void k_final(const float* scal, float* out) {
  if (threadIdx.x == 0) {
    float loss = scal[0] * (128.f / 4128.f);
    out[0] = loss;
    out[1] = scal[1] * (1.f / 4128.f);
    out[2] = expf(loss / 32.f);
  }
}

// --------------------------------- launch ----------------------------------
extern "C" void kernel_launch(void* const* d_in, const int* in_sizes, int n_in,
                              void* d_out, int out_size, void* d_ws, size_t ws_size,
                              hipStream_t stream) {
  const float* hs_pad = (const float*)d_in[0];
  const int* hlens    = (const int*)d_in[1];
  const int* ys_pad   = (const int*)d_in[2];
  const float* embed  = (const float*)d_in[3];
  const float* Wenc   = (const float*)d_in[4];
  const float* benc   = (const float*)d_in[5];
  const float* Wdec   = (const float*)d_in[6];
  const float* Wih0   = (const float*)d_in[7];
  const float* Whh0   = (const float*)d_in[8];
  const float* bih0   = (const float*)d_in[9];
  const float* bhh0   = (const float*)d_in[10];
  const float* Wih1   = (const float*)d_in[11];
  const float* Whh1   = (const float*)d_in[12];
  const float* bih1   = (const float*)d_in[13];
  const float* bhh1   = (const float*)d_in[14];
  const float* Wout   = (const float*)d_in[15];
  const float* bout   = (const float*)d_in[16];
  float* out = (float*)d_out;
  (void)in_sizes; (void)n_in; (void)out_size; (void)ws_size;

  char* ws = (char*)d_ws;
  size_t off = 0;
  auto alloc = [&](size_t bytes) -> char* {
    char* pp = ws + off;
    off = (off + bytes + 255) & ~(size_t)255;
    return pp;
  };
  f16* hs16    = (f16*)alloc((size_t)NB * NTT * NE * 2);
  f16* preT    = (f16*)alloc((size_t)NB * NA * NTT * 2);
  f16* eys16   = (f16*)alloc((size_t)NL * NB * ND * 2);
  f16* w0cat   = (f16*)alloc((size_t)4096 * 2560 * 2);
  f16* w1cat   = (f16*)alloc((size_t)4096 * 2048 * 2);
  f16* wdec16  = (f16*)alloc((size_t)NA * ND * 2);
  f16* wenc16  = (f16*)alloc((size_t)NA * NE * 2);
  f16* wout16  = (f16*)alloc((size_t)NO * ND * 2);
  f16* zout    = (f16*)alloc((size_t)NTOK * ND * 2);
  f16* z0h     = (f16*)alloc((size_t)NB * ND * 2);
  f16* z1h     = (f16*)alloc((size_t)NB * ND * 2);
  f16* dec16   = (f16*)alloc((size_t)NB * NA * 2);
  f16* att16   = (f16*)alloc((size_t)NB * NE * 2);
  float* bs0   = (float*)alloc(4096 * 4);
  float* bs1   = (float*)alloc(4096 * 4);
  float* tl    = (float*)alloc((size_t)NTOK * 4);
  float4* part = (float4*)alloc((size_t)NTOK * 80 * 16);
  float* scal  = (float*)alloc(256);
  unsigned* bar = (unsigned*)alloc(2048);

  k_cvt<<<dim3(2048), dim3(256), 0, stream>>>(hs_pad, hs16, (long)NB * NTT * NE);
  k_cvt<<<dim3(256), dim3(256), 0, stream>>>(Wdec, wdec16, (long)NA * ND);
  k_cvt<<<dim3(128), dim3(256), 0, stream>>>(Wenc, wenc16, (long)NA * NE);
  k_cvt<<<dim3(2048), dim3(256), 0, stream>>>(Wout, wout16, (long)NO * ND);
  k_w0cat<<<dim3(10, 4096), dim3(256), 0, stream>>>(Wih0, Whh0, w0cat);
  k_w1cat<<<dim3(8, 4096), dim3(256), 0, stream>>>(Wih1, Whh1, w1cat);
  k_eys<<<dim3(4, NL * NB), dim3(256), 0, stream>>>(ys_pad, embed, eys16);
  k_pre<<<dim3(512), dim3(256), 0, stream>>>(hs16, wenc16, benc, preT);
  k_bias<<<dim3(16), dim3(256), 0, stream>>>(bih0, bhh0, bih1, bhh1, bs0, bs1);
  k_zero<<<dim3(128), dim3(256), 0, stream>>>(dec16, z0h, z1h, scal, bar);

  LoopP lp;
  lp.preT = preT; lp.hs = hs16; lp.eys = eys16; lp.w0 = w0cat; lp.w1 = w1cat; lp.wdec = wdec16;
  lp.bs0 = bs0; lp.bs1 = bs1; lp.hlens = hlens;
  lp.dec = dec16; lp.att = att16; lp.z0h = z0h; lp.z1h = z1h; lp.zout = zout; lp.bar = bar;
  k_loop<<<dim3(GRID_LOOP), dim3(256), 0, stream>>>(lp);

  k_tl<<<dim3(NTOK / 4), dim3(256), 0, stream>>>(zout, wout16, bout, ys_pad, tl);
  k_lgemm<<<dim3(129, 20), dim3(256), 0, stream>>>(zout, wout16, bout, part);
  k_ce<<<dim3(17), dim3(256), 0, stream>>>(part, tl, ys_pad, scal);
  k_final<<<dim3(1), dim3(64), 0, stream>>>(scal, out);
}